// Round 7
// baseline (778.684 us; speedup 1.0000x reference)
//
#include <hip/hip_runtime.h>
#include <stdint.h>

#define FEAT 256
#define CODES 8192
#define NQ 16384                 // 16*32*32
#define ZQ_ELEMS (NQ * FEAT)
#define MARGIN 2e-3f             // = 2e bound on fp16 score error (R4-validated)
#define NSLICE 8
#define CAP_PAIRS (1 << 18)      // 256K (expected ~45K with fp8 slack)
#define KSC (-0.0078125f)        // descale: acc * -2/256
#define SCORES_OFF 31457280ull   // 30 MiB: right after fixed ws region

// Score-store format: fp8 e4m3 if the conversion builtins exist, else fp16.
#if __has_builtin(__builtin_amdgcn_cvt_pk_fp8_f32) && __has_builtin(__builtin_amdgcn_cvt_f32_fp8)
#define FP8SC 1
#define STORE_ERR 0.03125f       // e4m3 RNE abs err bound for |s| < 1 (threshold region)
#define SC_FULL_BYTES 134217728ull
#else
#define FP8SC 0
#define STORE_ERR 1.0e-3f        // fp16 RNE abs err bound for |s| < 2
#define SC_FULL_BYTES 268435456ull
#endif

typedef _Float16 f16x8 __attribute__((ext_vector_type(8)));
typedef float f32x4 __attribute__((ext_vector_type(4)));

__device__ __forceinline__ void async_lds16(void* lds, const void* g) {
  __builtin_amdgcn_global_load_lds(
      (const __attribute__((address_space(1))) void*)(uintptr_t)(g),
      (__attribute__((address_space(3))) void*)(uint32_t)(uintptr_t)(lds),
      16, 0, 0);
}

// monotone float<->uint order transform
__device__ __forceinline__ unsigned f2mono(float v) {
  unsigned u = __float_as_uint(v);
  return (u & 0x80000000u) ? ~u : (u | 0x80000000u);
}
__device__ __forceinline__ float mono2f(unsigned t) {
  unsigned u = (t & 0x80000000u) ? (t & 0x7fffffffu) : ~t;
  return __uint_as_float(u);
}
__device__ __forceinline__ unsigned pack_f16x2(float a, float b) {
  unsigned short ha = __builtin_bit_cast(unsigned short, (_Float16)a);
  unsigned short hb = __builtin_bit_cast(unsigned short, (_Float16)b);
  return (unsigned)ha | ((unsigned)hb << 16);
}
#if FP8SC
__device__ __forceinline__ unsigned pack_fp8x4(float a, float b, float c, float d) {
  int v = __builtin_amdgcn_cvt_pk_fp8_f32(a, b, 0, false);   // bytes 0,1
  v = __builtin_amdgcn_cvt_pk_fp8_f32(c, d, v, true);        // bytes 2,3
  return (unsigned)v;
}
#endif

// ---------------------------------------------------------------------------
// numpy pairwise sum-of-squares replication (verified R1-R4, absmax 0).
// ---------------------------------------------------------------------------
template <int STRIDE>
__device__ __forceinline__ float pairwise256_sq(const float* __restrict__ base, int lane16) {
  const int h = lane16 >> 3, j = lane16 & 7;
  const float* p = base + (h * 128 + j) * STRIDE;
  float x = p[0];
  float r = __fmul_rn(x, x);
#pragma unroll
  for (int i = 1; i < 16; ++i) {
    float y = p[i * 8 * STRIDE];
    r = __fadd_rn(r, __fmul_rn(y, y));
  }
  r = __fadd_rn(r, __shfl_xor(r, 1, 64));
  r = __fadd_rn(r, __shfl_xor(r, 2, 64));
  r = __fadd_rn(r, __shfl_xor(r, 4, 64));
  float other = __shfl_xor(r, 8, 64);
  float lo = (h == 0) ? r : other;
  float hi = (h == 0) ? other : r;
  return __fadd_rn(lo, hi);
}

__global__ __launch_bounds__(256) void norms_kernel(const float* __restrict__ cb,
                                                    const float* __restrict__ z,
                                                    float* __restrict__ cbnorm,
                                                    float* __restrict__ znorm) {
  const int g = (blockIdx.x * 256 + threadIdx.x) >> 4;
  const int lane16 = threadIdx.x & 15;
  if (g < CODES) {
    float v = pairwise256_sq<1>(cb + g * FEAT, lane16);
    if (lane16 == 0) cbnorm[g] = v;
  } else {
    const int q = g - CODES;
    const int b = q >> 10, hw = q & 1023;
    float v = pairwise256_sq<1024>(z + b * (FEAT * 1024) + hw, lane16);
    if (lane16 == 0) znorm[q] = v;
  }
}

// ---------------------------------------------------------------------------
// convA: z fp32 -> fp16 tiles [mt][ct][r128][c32] + fp32 transpose zT[q][c]
// ---------------------------------------------------------------------------
__global__ __launch_bounds__(256) void convA(const float* __restrict__ z,
                                             char* __restrict__ At, float* __restrict__ zT) {
  __shared__ _Float16 T[128 * 40];
  __shared__ float Tf[128 * 36];
  const int t = threadIdx.x;
  const int mt = blockIdx.x >> 3, ct = blockIdx.x & 7;
  const int q0 = mt * 128, bb = q0 >> 10, hw0 = q0 & 1023;
  const int c0 = ct * 32;
#pragma unroll
  for (int it = 0; it < 16; ++it) {
    const int cc = it * 2 + (t >> 7);
    const int qi = t & 127;
    float v = z[bb * (FEAT * 1024) + (c0 + cc) * 1024 + hw0 + qi];
    T[qi * 40 + cc] = (_Float16)v;
    Tf[qi * 36 + cc] = v;
  }
  __syncthreads();
  const int r = t >> 1, h = t & 1;
  {
    float4 a = *(const float4*)&T[r * 40 + h * 16];
    float4 b = *(const float4*)&T[r * 40 + h * 16 + 8];
    char* dst = At + (size_t)(mt * 8 + ct) * 8192 + t * 32;
    *(float4*)dst = a;
    *(float4*)(dst + 16) = b;
  }
  float* zrow = zT + (size_t)(q0 + r) * FEAT + c0 + h * 16;
#pragma unroll
  for (int e = 0; e < 4; ++e)
    *(float4*)(zrow + e * 4) = *(const float4*)&Tf[r * 36 + h * 16 + e * 4];
}

// ---------------------------------------------------------------------------
// convB: cb fp32 -> fp16 FRAGMENT-LINEAR layout, scaled by 256.
// Verified absmax 0 in R1/R2/R4/R5.
// ---------------------------------------------------------------------------
__global__ __launch_bounds__(256) void convB(const float* __restrict__ cb, char* __restrict__ Bt) {
  const int T = blockIdx.x * 256 + threadIdx.x;   // [0, 131072)
  const int K = T >> 4, part = T & 15;            // K: code row; part: 16-float chunk
  const float* src = cb + (size_t)K * FEAT + part * 16;
  const int nt = K >> 7, rem = K & 127;
  const int wn = rem >> 6, j = (rem >> 4) & 3, llo = rem & 15;
#pragma unroll
  for (int g = 0; g < 2; ++g) {
    const int c0 = part * 16 + g * 8;
    const int ct = c0 >> 5, lhi = (c0 >> 3) & 3;
    const int cg = nt * 8 + ct;
    f16x8 o;
#pragma unroll
    for (int e = 0; e < 8; ++e) o[e] = (_Float16)(src[g * 8 + e] * 256.0f);
    const size_t s = ((size_t)((cg * 2 + wn) * 4 + j) << 6) + (size_t)(lhi * 16 + llo);
    *(f16x8*)(Bt + s * 16) = o;
  }
}

// ---------------------------------------------------------------------------
// Shared GEMM body, R2-proven structure: A-tile (64 KB, all K) resident in
// LDS; B chunks (8 KB) double-buffered via global_load_lds, counted vmcnt(2)
// waits, raw s_barriers, sched_barrier(0) fences.
// PASS=0: per-row running min -> atomicMin gmin[q].
// PASS=1: (fallback pass2) push (q<<13|k) for score <= gmin[q]+MARGIN.
// PASS=2: PASS0 + store all scores packed (fp8x4 or fp16x2) fragment order.
// mt0: query-group mt offset (store index uses LOCAL blockIdx.x).
// ---------------------------------------------------------------------------
template <int PASS>
__device__ __forceinline__ void gemm_body(const char* __restrict__ At,
                                          const char* __restrict__ Bt,
                                          const float* __restrict__ cbnorm,
                                          unsigned* __restrict__ gmin,
                                          unsigned* __restrict__ pairs,
                                          int* __restrict__ paircount,
                                          unsigned* __restrict__ scores, int mt0) {
  __shared__ __align__(16) char Af[65536];
  __shared__ __align__(16) char Bs0[8192];
  __shared__ __align__(16) char Bs1[8192];

  const int tid = threadIdx.x;
  const int slice = blockIdx.x & 7, mt = (blockIdx.x >> 3) + mt0;
  const int wave = tid >> 6, lane = tid & 63;
  const int wm = wave >> 1, wn = wave & 1;
  const int col = lane & 15, quad = lane >> 4;

  const int srow = wave * 32 + (lane >> 2);  // A staging row within 32-row group
  const int ss = lane & 3;
  const char* Abase = At + (size_t)(mt * 8) * 8192;
  const char* Bslice = Bt + (size_t)slice * 524288;

  // stage entire A tile (8 ct-chunks) into LDS, swizzled slots
#pragma unroll
  for (int ct = 0; ct < 8; ++ct) {
#pragma unroll
    for (int i = 0; i < 2; ++i) {
      const int r = srow + i * 16;
      const int cs = ss ^ ((r >> 1) & 3);
      async_lds16(Af + ct * 8192 + wave * 2048 + i * 1024,
                  Abase + (size_t)ct * 8192 + r * 64 + cs * 16);
    }
  }

#define STAGE_B(BUF, CIDX)                                                          \
  do {                                                                              \
    const char* gs_ = Bslice + ((size_t)(CIDX) << 13) + wave * 2048 + lane * 16;    \
    async_lds16((BUF) + wave * 2048, gs_);                                          \
    async_lds16((BUF) + wave * 2048 + 1024, gs_ + 1024);                            \
  } while (0)

  // prime double-buffer: chunks 0 and 1
  STAGE_B(Bs0, 0);
  STAGE_B(Bs1, 1);

  int aoff[4];
#pragma unroll
  for (int i = 0; i < 4; ++i) {
    const int m = wm * 64 + i * 16 + col;
    aoff[i] = m * 64 + ((quad ^ ((m >> 1) & 3)) << 4);
  }

  int qrow[16];
#pragma unroll
  for (int row = 0; row < 16; ++row)
    qrow[row] = mt * 128 + wm * 64 + (row >> 2) * 16 + quad * 4 + (row & 3);

  float vmin[16], thr[16];
#pragma unroll
  for (int row = 0; row < 16; ++row) vmin[row] = 3.4e38f;
  if (PASS == 1) {
#pragma unroll
    for (int row = 0; row < 16; ++row) thr[row] = mono2f(gmin[qrow[row]]) + MARGIN;
  }

  f32x4 acc[4][4];

  __syncthreads();  // full drain once: A tile + B chunks 0,1 landed

  // Per-chunk step. WMODE 2: s_waitcnt vmcnt(2) -- the 2 newest outstanding
  // VMEM ops are this chunk's stage(c+2); everything older (incl. stage(c+1)
  // and any score stores) is complete. 0: drain. 3: no wait (final chunk).
#define CHUNK(CT, STG, CNEXT, WMODE)                                                \
  do {                                                                              \
    char* Bcur_ = ((CT) & 1) ? Bs1 : Bs0;                                           \
    f16x8 bf_[4], af_[4];                                                           \
    _Pragma("unroll") for (int j = 0; j < 4; ++j)                                   \
        bf_[j] = *(const f16x8*)(Bcur_ + wn * 4096 + j * 1024 + lane * 16);         \
    _Pragma("unroll") for (int i = 0; i < 4; ++i)                                   \
        af_[i] = *(const f16x8*)(Af + (CT) * 8192 + aoff[i]);                       \
    asm volatile("s_waitcnt lgkmcnt(0)" ::: "memory");                              \
    __builtin_amdgcn_sched_barrier(0);                                              \
    __builtin_amdgcn_s_barrier(); /* all waves done reading Bcur_ */                \
    if (STG) {                                                                      \
      STAGE_B(Bcur_, CNEXT);                                                        \
      __builtin_amdgcn_sched_barrier(0); /* keep loads issued before MFMA */        \
    }                                                                               \
    _Pragma("unroll") for (int i = 0; i < 4; ++i)                                   \
        _Pragma("unroll") for (int j = 0; j < 4; ++j)                               \
            acc[i][j] = __builtin_amdgcn_mfma_f32_16x16x32_f16(af_[i], bf_[j],      \
                                                               acc[i][j], 0, 0, 0); \
    if ((WMODE) == 2) {                                                             \
      asm volatile("s_waitcnt vmcnt(2)" ::: "memory");                              \
      __builtin_amdgcn_sched_barrier(0);                                            \
    }                                                                               \
    if ((WMODE) == 0) {                                                             \
      asm volatile("s_waitcnt vmcnt(0)" ::: "memory");                              \
      __builtin_amdgcn_sched_barrier(0);                                            \
    }                                                                               \
    __builtin_amdgcn_s_barrier(); /* next buffer staged for all waves */            \
  } while (0)

#define ZEROACC                                                                     \
  do {                                                                              \
    _Pragma("unroll") for (int i = 0; i < 4; ++i)                                   \
        _Pragma("unroll") for (int j = 0; j < 4; ++j)                               \
            acc[i][j] = (f32x4){0.f, 0.f, 0.f, 0.f};                                \
  } while (0)

#if FP8SC
#define SC_TILE_STRIDE 16u
#define STORE_ROW(SB, ROW, A, B, C, D) (SB)[(unsigned)((ROW) * 64)] = pack_fp8x4(A, B, C, D)
#else
#define SC_TILE_STRIDE 32u
#define STORE_ROW(SB, ROW, A, B, C, D)                                              \
  do {                                                                              \
    (SB)[(unsigned)(((ROW) * 2 + 0) * 64)] = pack_f16x2(A, B);                      \
    (SB)[(unsigned)(((ROW) * 2 + 1) * 64)] = pack_f16x2(C, D);                      \
  } while (0)
#endif

#define SCORING(NT)                                                                 \
  do {                                                                              \
    const int k0_ = (slice * 8 + (NT)) * 128;                                       \
    float cn_[4];                                                                   \
    _Pragma("unroll") for (int j = 0; j < 4; ++j)                                   \
        cn_[j] = cbnorm[k0_ + wn * 64 + j * 16 + col];                              \
    unsigned* sb_ = (PASS == 2)                                                     \
        ? scores + ((((unsigned)blockIdx.x * 8u + (unsigned)(NT)) * 4u +            \
                     (unsigned)wave) * SC_TILE_STRIDE) * 64u + (unsigned)lane       \
        : nullptr;                                                                  \
    _Pragma("unroll") for (int i = 0; i < 4; ++i)                                   \
        _Pragma("unroll") for (int r = 0; r < 4; ++r) {                             \
      const int row_ = i * 4 + r;                                                   \
      const float s0_ = __builtin_fmaf(acc[i][0][r], KSC, cn_[0]);                  \
      const float s1_ = __builtin_fmaf(acc[i][1][r], KSC, cn_[1]);                  \
      const float s2_ = __builtin_fmaf(acc[i][2][r], KSC, cn_[2]);                  \
      const float s3_ = __builtin_fmaf(acc[i][3][r], KSC, cn_[3]);                  \
      const float rm_ = fminf(fminf(s0_, s1_), fminf(s2_, s3_));                    \
      if (PASS != 1) {                                                              \
        vmin[row_] = fminf(vmin[row_], rm_);                                        \
        if (PASS == 2) {                                                            \
          STORE_ROW(sb_, row_, s0_, s1_, s2_, s3_);                                 \
        }                                                                           \
      } else if (rm_ <= thr[row_]) { /* exact early-out: min_j > thr => none */     \
        const float sv_[4] = {s0_, s1_, s2_, s3_};                                  \
        _Pragma("unroll") for (int j = 0; j < 4; ++j) {                             \
          if (sv_[j] <= thr[row_]) {                                                \
            const int slot_ = atomicAdd(paircount, 1);                              \
            if (slot_ < CAP_PAIRS)                                                  \
              pairs[slot_] = ((unsigned)qrow[row_] << 13) |                         \
                             (unsigned)(k0_ + wn * 64 + j * 16 + col);              \
          }                                                                         \
        }                                                                           \
      }                                                                             \
    }                                                                               \
  } while (0)

  for (int nt = 0; nt < 7; ++nt) {
    ZEROACC;
#pragma unroll
    for (int ct = 0; ct < 8; ++ct) CHUNK(ct, true, nt * 8 + ct + 2, 2);
    SCORING(nt);
  }
  // nt = 7 epilogue: stop staging at chunk 63, then drain
  ZEROACC;
  CHUNK(0, true, 58, 2);
  CHUNK(1, true, 59, 2);
  CHUNK(2, true, 60, 2);
  CHUNK(3, true, 61, 2);
  CHUNK(4, true, 62, 2);
  CHUNK(5, true, 63, 2);
  CHUNK(6, false, 0, 0);
  CHUNK(7, false, 0, 3);
  SCORING(7);

#undef STAGE_B
#undef CHUNK
#undef ZEROACC
#undef SCORING
#undef STORE_ROW

  if (PASS != 1) {
    // cross-col min (value only), then atomicMin per row
#pragma unroll
    for (int row = 0; row < 16; ++row) {
      float v = vmin[row];
      v = fminf(v, __shfl_xor(v, 1, 64));
      v = fminf(v, __shfl_xor(v, 2, 64));
      v = fminf(v, __shfl_xor(v, 4, 64));
      v = fminf(v, __shfl_xor(v, 8, 64));
      if (col == 0) atomicMin(&gmin[qrow[row]], f2mono(v));
    }
  }
}

__global__ __launch_bounds__(256, 2) void gemm_pass1(const char* __restrict__ At,
                                                     const char* __restrict__ Bt,
                                                     const float* __restrict__ cbnorm,
                                                     unsigned* __restrict__ gmin) {
  gemm_body<0>(At, Bt, cbnorm, gmin, nullptr, nullptr, nullptr, 0);
}

__global__ __launch_bounds__(256, 2) void gemm_pass1s(const char* __restrict__ At,
                                                      const char* __restrict__ Bt,
                                                      const float* __restrict__ cbnorm,
                                                      unsigned* __restrict__ gmin,
                                                      unsigned* __restrict__ scores, int mt0) {
  gemm_body<2>(At, Bt, cbnorm, gmin, nullptr, nullptr, scores, mt0);
}

__global__ __launch_bounds__(256, 2) void gemm_pass2(const char* __restrict__ At,
                                                     const char* __restrict__ Bt,
                                                     const float* __restrict__ cbnorm,
                                                     unsigned* __restrict__ gmin,
                                                     unsigned* __restrict__ pairs,
                                                     int* __restrict__ paircount) {
  gemm_body<1>(At, Bt, cbnorm, gmin, pairs, paircount, nullptr, 0);
}

// ---------------------------------------------------------------------------
// scan_scores: stream the packed score matrix (one q-group), push (q,k) for
// every stored score <= gmin[q] + MARGIN + STORE_ERR. Superset of the
// two-pass candidate set (stored <= true + err, err <= STORE_ERR in the
// threshold region |s| < 1); exact_cand's fp32 rescore picks the identical
// deterministic winner. One uint4 = 16 (fp8) / 8 (fp16) scores of ONE q.
// ---------------------------------------------------------------------------
__global__ __launch_bounds__(256) void scan_scores(const unsigned* __restrict__ scores,
                                                   const unsigned* __restrict__ gmin,
                                                   unsigned* __restrict__ pairs,
                                                   int* __restrict__ paircount,
                                                   int qbase, unsigned NU4) {
  const unsigned stride = gridDim.x * blockDim.x;
  for (unsigned U = blockIdx.x * 256 + threadIdx.x; U < NU4; U += stride) {
    const uint4 v = ((const uint4*)scores)[U];
    const unsigned u = U << 2;
    const unsigned lane0 = u & 63, col0 = lane0 & 15, quad = lane0 >> 4;
#if FP8SC
    const unsigned row = (u >> 6) & 15;
    const unsigned wave = (u >> 10) & 3;
    const unsigned nt = (u >> 12) & 7;
    const unsigned blk = u >> 15;
#else
    const unsigned e32 = (u >> 6) & 31;
    const unsigned row = e32 >> 1, jp = e32 & 1;
    const unsigned wave = (u >> 11) & 3;
    const unsigned nt = (u >> 13) & 7;
    const unsigned blk = u >> 16;
#endif
    const unsigned mtl = blk >> 3, slice = blk & 7;
    const unsigned wm = wave >> 1, wn = wave & 1;
    const int q = qbase + (int)(mtl * 128u + wm * 64u + (row >> 2) * 16u + quad * 4u + (row & 3u));
    const float thr = mono2f(gmin[q]) + (MARGIN + STORE_ERR);
    const unsigned wv[4] = {v.x, v.y, v.z, v.w};
#pragma unroll
    for (int w = 0; w < 4; ++w) {
#if FP8SC
      const int kb = (int)(slice * 1024u + nt * 128u + wn * 64u + col0) + w;
      float sj[4];
      sj[0] = __builtin_amdgcn_cvt_f32_fp8((int)wv[w], 0);
      sj[1] = __builtin_amdgcn_cvt_f32_fp8((int)wv[w], 1);
      sj[2] = __builtin_amdgcn_cvt_f32_fp8((int)wv[w], 2);
      sj[3] = __builtin_amdgcn_cvt_f32_fp8((int)wv[w], 3);
#pragma unroll
      for (int j = 0; j < 4; ++j) {
        if (sj[j] <= thr) {
          const int slot = atomicAdd(paircount, 1);
          if (slot < CAP_PAIRS) pairs[slot] = ((unsigned)q << 13) | (unsigned)(kb + j * 16);
        }
      }
#else
      const int kb = (int)(slice * 1024u + nt * 128u + wn * 64u + jp * 32u + col0) + w;
      const float slo = (float)__builtin_bit_cast(_Float16, (unsigned short)(wv[w] & 0xffffu));
      const float shi = (float)__builtin_bit_cast(_Float16, (unsigned short)(wv[w] >> 16));
      if (slo <= thr) {
        const int slot = atomicAdd(paircount, 1);
        if (slot < CAP_PAIRS) pairs[slot] = ((unsigned)q << 13) | (unsigned)kb;
      }
      if (shi <= thr) {
        const int slot = atomicAdd(paircount, 1);
        if (slot < CAP_PAIRS) pairs[slot] = ((unsigned)q << 13) | (unsigned)(kb + 16);
      }
#endif
    }
  }
}

// ---------------------------------------------------------------------------
// Exact fp32 rescore of all pushed pairs (np chain, R4-verified machinery).
// One wave per pair; winner per q via packed atomicMin (ties -> min k).
// ---------------------------------------------------------------------------
__global__ __launch_bounds__(256) void exact_cand(const float* __restrict__ zT,
                                                  const float* __restrict__ cb,
                                                  const float* __restrict__ cbnorm,
                                                  const float* __restrict__ znorm,
                                                  const unsigned* __restrict__ pairs,
                                                  const int* __restrict__ paircount,
                                                  unsigned long long* __restrict__ packed) {
  const int cnt = min(*paircount, CAP_PAIRS);
  const int gw = (blockIdx.x * 256 + threadIdx.x) >> 6;
  const int nw = (gridDim.x * 256) >> 6;
  const int lane = threadIdx.x & 63;
  for (int p = gw; p < cnt; p += nw) {
    const unsigned qk = pairs[p];
    const int q = qk >> 13, k = qk & 8191;
    const float4 cv = ((const float4*)(cb + (size_t)k * FEAT))[lane];
    const float4 zv = ((const float4*)(zT + (size_t)q * FEAT))[lane];
    float d = __builtin_fmaf(zv.w, cv.w,
              __builtin_fmaf(zv.z, cv.z,
              __builtin_fmaf(zv.y, cv.y, __fmul_rn(zv.x, cv.x))));
#pragma unroll
    for (int dd = 1; dd < 64; dd <<= 1) d = __fadd_rn(d, __shfl_xor(d, dd, 64));
    const float s = __fadd_rn(__fadd_rn(__fmul_rn(-2.0f, d), znorm[q]), cbnorm[k]);
    if (lane == 0) {
      const unsigned long long key = ((unsigned long long)f2mono(s) << 32) | (unsigned)k;
      atomicMin(&packed[q], key);
    }
  }
}

// ---------------------------------------------------------------------------
// Gather: zq[b][c][hw] = cb[idx]; idx as float appended after zq.
// ---------------------------------------------------------------------------
__global__ __launch_bounds__(256) void vq_gather(const float* __restrict__ cb,
                                                 const unsigned long long* __restrict__ packed,
                                                 float* __restrict__ out) {
  const int q0 = blockIdx.x * 64;
  const int nl = threadIdx.x & 63;
  const int cg = threadIdx.x >> 6;
  const int q = q0 + nl;
  const int kq = (int)((unsigned)packed[q] & 8191u);
  const int b = q >> 10, hw = q & 1023;
  const float4* cb4 = (const float4*)cb;
#pragma unroll
  for (int t = 0; t < 16; ++t) {
    const int cc = cg + t * 4;
    const float4 v = cb4[kq * 64 + cc];
    const int base = b * (FEAT * 1024) + (cc * 4) * 1024 + hw;
    out[base] = v.x;
    out[base + 1024] = v.y;
    out[base + 2048] = v.z;
    out[base + 3072] = v.w;
  }
  if (threadIdx.x < 64) {
    const int qq = q0 + threadIdx.x;
    out[ZQ_ELEMS + qq] = (float)(int)((unsigned)packed[qq] & 8191u);
  }
}

extern "C" void kernel_launch(void* const* d_in, const int* in_sizes, int n_in,
                              void* d_out, int out_size, void* d_ws, size_t ws_size,
                              hipStream_t stream) {
  const float* z = (const float*)d_in[0];
  const float* cb = (const float*)d_in[1];
  char* w = (char*)d_ws;
  // ws layout: ~30 MiB fixed + adaptive score buffer at SCORES_OFF
  char* At = w;                                            // 8 MB
  char* Bt = w + 8388608;                                  // 4 MB
  float* zT = (float*)(w + 12582912);                      // 16 MB
  float* cbnorm = (float*)(w + 29360128);                  // 32 KB
  float* znorm = (float*)(w + 29392896);                   // 64 KB
  unsigned* gmin = (unsigned*)(w + 29458432);              // 64 KB
  int* paircount = (int*)(w + 29523968);                   // 256 B
  unsigned* pairs = (unsigned*)(w + 29524224);             // 1 MB (256K pairs)
  unsigned long long* packed = (unsigned long long*)(w + 30572800);  // 128 KB
  unsigned* scores = (unsigned*)(w + SCORES_OFF);          // 128MiB/G (fp8) packed scores

  // adaptive q-group count: largest score buffer that fits
  const size_t avail = ws_size > (size_t)SCORES_OFF ? ws_size - (size_t)SCORES_OFF : 0;
  int G = 0;
  if (avail >= SC_FULL_BYTES) G = 1;
  else if (avail >= (SC_FULL_BYTES >> 1)) G = 2;
  else if (avail >= (SC_FULL_BYTES >> 2)) G = 4;

  hipMemsetAsync(paircount, 0, 256, stream);
  hipMemsetAsync(gmin, 0xFF, NQ * sizeof(unsigned), stream);
  hipMemsetAsync(packed, 0xFF, NQ * sizeof(unsigned long long), stream);
  norms_kernel<<<(CODES + NQ) / 16, 256, 0, stream>>>(cb, z, cbnorm, znorm);
  convA<<<1024, 256, 0, stream>>>(z, At, zT);
  convB<<<512, 256, 0, stream>>>(cb, Bt);
  if (G) {
    const int mtg = 128 / G;  // mt-tiles per group
    const unsigned nu4 = (unsigned)((SC_FULL_BYTES / (unsigned long long)G) >> 4);
    for (int g = 0; g < G; ++g) {
      gemm_pass1s<<<mtg * 8, 256, 0, stream>>>(At, Bt, cbnorm, gmin, scores, g * mtg);
      scan_scores<<<2048, 256, 0, stream>>>(scores, gmin, pairs, paircount, g * mtg * 128, nu4);
    }
  } else {
    gemm_pass1<<<(NQ / 128) * NSLICE, 256, 0, stream>>>(At, Bt, cbnorm, gmin);
    gemm_pass2<<<(NQ / 128) * NSLICE, 256, 0, stream>>>(At, Bt, cbnorm, gmin, pairs, paircount);
  }
  exact_cand<<<512, 256, 0, stream>>>(zT, cb, cbnorm, znorm, pairs, paircount, packed);
  vq_gather<<<NQ / 64, 256, 0, stream>>>(cb, packed, (float*)d_out);
}

// Round 8
// 406.940 us; speedup vs baseline: 1.9135x; 1.9135x over previous
//
#include <hip/hip_runtime.h>
#include <stdint.h>

#define FEAT 256
#define CODES 8192
#define NQ 16384                 // 16*32*32
#define ZQ_ELEMS (NQ * FEAT)
#define MARGIN 2e-3f             // = 2e bound on fp16 score error (R4-validated)
#define RM_ERR 1.0e-3f           // fp16 RNE storage err bound for |rm| < 2
#define NSLICE 8
#define CAP_PAIRS (1 << 18)      // 256K (expected ~20K groups)
#define KSC (-0.0078125f)        // descale: acc * -2/256
#define MEMO_OFF 31457280ull     // 30 MiB: right after fixed ws region
#define MEMO_BYTES 67108864ull   // 64 MiB fp16 group-mins

typedef _Float16 f16x8 __attribute__((ext_vector_type(8)));
typedef float f32x4 __attribute__((ext_vector_type(4)));

__device__ __forceinline__ void async_lds16(void* lds, const void* g) {
  __builtin_amdgcn_global_load_lds(
      (const __attribute__((address_space(1))) void*)(uintptr_t)(g),
      (__attribute__((address_space(3))) void*)(uint32_t)(uintptr_t)(lds),
      16, 0, 0);
}

// monotone float<->uint order transform
__device__ __forceinline__ unsigned f2mono(float v) {
  unsigned u = __float_as_uint(v);
  return (u & 0x80000000u) ? ~u : (u | 0x80000000u);
}
__device__ __forceinline__ float mono2f(unsigned t) {
  unsigned u = (t & 0x80000000u) ? (t & 0x7fffffffu) : ~t;
  return __uint_as_float(u);
}
__device__ __forceinline__ unsigned pack_f16x2(float a, float b) {
  unsigned short ha = __builtin_bit_cast(unsigned short, (_Float16)a);
  unsigned short hb = __builtin_bit_cast(unsigned short, (_Float16)b);
  return (unsigned)ha | ((unsigned)hb << 16);
}

// ---------------------------------------------------------------------------
// numpy pairwise sum-of-squares replication (verified R1-R4, absmax 0).
// ---------------------------------------------------------------------------
template <int STRIDE>
__device__ __forceinline__ float pairwise256_sq(const float* __restrict__ base, int lane16) {
  const int h = lane16 >> 3, j = lane16 & 7;
  const float* p = base + (h * 128 + j) * STRIDE;
  float x = p[0];
  float r = __fmul_rn(x, x);
#pragma unroll
  for (int i = 1; i < 16; ++i) {
    float y = p[i * 8 * STRIDE];
    r = __fadd_rn(r, __fmul_rn(y, y));
  }
  r = __fadd_rn(r, __shfl_xor(r, 1, 64));
  r = __fadd_rn(r, __shfl_xor(r, 2, 64));
  r = __fadd_rn(r, __shfl_xor(r, 4, 64));
  float other = __shfl_xor(r, 8, 64);
  float lo = (h == 0) ? r : other;
  float hi = (h == 0) ? other : r;
  return __fadd_rn(lo, hi);
}

__global__ __launch_bounds__(256) void norms_kernel(const float* __restrict__ cb,
                                                    const float* __restrict__ z,
                                                    float* __restrict__ cbnorm,
                                                    float* __restrict__ znorm) {
  const int g = (blockIdx.x * 256 + threadIdx.x) >> 4;
  const int lane16 = threadIdx.x & 15;
  if (g < CODES) {
    float v = pairwise256_sq<1>(cb + g * FEAT, lane16);
    if (lane16 == 0) cbnorm[g] = v;
  } else {
    const int q = g - CODES;
    const int b = q >> 10, hw = q & 1023;
    float v = pairwise256_sq<1024>(z + b * (FEAT * 1024) + hw, lane16);
    if (lane16 == 0) znorm[q] = v;
  }
}

// ---------------------------------------------------------------------------
// convA: z fp32 -> fp16 tiles [mt][ct][r128][c32] + fp32 transpose zT[q][c]
// ---------------------------------------------------------------------------
__global__ __launch_bounds__(256) void convA(const float* __restrict__ z,
                                             char* __restrict__ At, float* __restrict__ zT) {
  __shared__ _Float16 T[128 * 40];
  __shared__ float Tf[128 * 36];
  const int t = threadIdx.x;
  const int mt = blockIdx.x >> 3, ct = blockIdx.x & 7;
  const int q0 = mt * 128, bb = q0 >> 10, hw0 = q0 & 1023;
  const int c0 = ct * 32;
#pragma unroll
  for (int it = 0; it < 16; ++it) {
    const int cc = it * 2 + (t >> 7);
    const int qi = t & 127;
    float v = z[bb * (FEAT * 1024) + (c0 + cc) * 1024 + hw0 + qi];
    T[qi * 40 + cc] = (_Float16)v;
    Tf[qi * 36 + cc] = v;
  }
  __syncthreads();
  const int r = t >> 1, h = t & 1;
  {
    float4 a = *(const float4*)&T[r * 40 + h * 16];
    float4 b = *(const float4*)&T[r * 40 + h * 16 + 8];
    char* dst = At + (size_t)(mt * 8 + ct) * 8192 + t * 32;
    *(float4*)dst = a;
    *(float4*)(dst + 16) = b;
  }
  float* zrow = zT + (size_t)(q0 + r) * FEAT + c0 + h * 16;
#pragma unroll
  for (int e = 0; e < 4; ++e)
    *(float4*)(zrow + e * 4) = *(const float4*)&Tf[r * 36 + h * 16 + e * 4];
}

// ---------------------------------------------------------------------------
// convB: cb fp32 -> fp16 FRAGMENT-LINEAR layout, scaled by 256.
// Verified absmax 0 in R1/R2/R4/R5/R7.
// ---------------------------------------------------------------------------
__global__ __launch_bounds__(256) void convB(const float* __restrict__ cb, char* __restrict__ Bt) {
  const int T = blockIdx.x * 256 + threadIdx.x;   // [0, 131072)
  const int K = T >> 4, part = T & 15;            // K: code row; part: 16-float chunk
  const float* src = cb + (size_t)K * FEAT + part * 16;
  const int nt = K >> 7, rem = K & 127;
  const int wn = rem >> 6, j = (rem >> 4) & 3, llo = rem & 15;
#pragma unroll
  for (int g = 0; g < 2; ++g) {
    const int c0 = part * 16 + g * 8;
    const int ct = c0 >> 5, lhi = (c0 >> 3) & 3;
    const int cg = nt * 8 + ct;
    f16x8 o;
#pragma unroll
    for (int e = 0; e < 8; ++e) o[e] = (_Float16)(src[g * 8 + e] * 256.0f);
    const size_t s = ((size_t)((cg * 2 + wn) * 4 + j) << 6) + (size_t)(lhi * 16 + llo);
    *(f16x8*)(Bt + s * 16) = o;
  }
}

// ---------------------------------------------------------------------------
// Shared GEMM body, R2-proven structure: A-tile (64 KB, all K) resident in
// LDS; B chunks (8 KB) double-buffered via global_load_lds, counted vmcnt(2)
// waits, raw s_barriers, sched_barrier(0) fences.
// PASS=0: per-row running min -> atomicMin gmin[q].
// PASS=1: (fallback pass2) push (q<<13|k) for score <= gmin[q]+MARGIN.
// PASS=3: PASS0 + store per-(row,tile) 4-k group-min rm_ as packed fp16x2.
//         memo layout (uints): ((((blk*8+nt)*4+wave)*8)+rp)*64 + lane,
//         uint = f16x2(rm[2rp], rm[2rp+1]). 64 MiB total.
// ---------------------------------------------------------------------------
template <int PASS>
__device__ __forceinline__ void gemm_body(const char* __restrict__ At,
                                          const char* __restrict__ Bt,
                                          const float* __restrict__ cbnorm,
                                          unsigned* __restrict__ gmin,
                                          unsigned* __restrict__ pairs,
                                          int* __restrict__ paircount,
                                          unsigned* __restrict__ memo) {
  __shared__ __align__(16) char Af[65536];
  __shared__ __align__(16) char Bs0[8192];
  __shared__ __align__(16) char Bs1[8192];

  const int tid = threadIdx.x;
  const int slice = blockIdx.x & 7, mt = blockIdx.x >> 3;
  const int wave = tid >> 6, lane = tid & 63;
  const int wm = wave >> 1, wn = wave & 1;
  const int col = lane & 15, quad = lane >> 4;

  const int srow = wave * 32 + (lane >> 2);  // A staging row within 32-row group
  const int ss = lane & 3;
  const char* Abase = At + (size_t)(mt * 8) * 8192;
  const char* Bslice = Bt + (size_t)slice * 524288;

  // stage entire A tile (8 ct-chunks) into LDS, swizzled slots
#pragma unroll
  for (int ct = 0; ct < 8; ++ct) {
#pragma unroll
    for (int i = 0; i < 2; ++i) {
      const int r = srow + i * 16;
      const int cs = ss ^ ((r >> 1) & 3);
      async_lds16(Af + ct * 8192 + wave * 2048 + i * 1024,
                  Abase + (size_t)ct * 8192 + r * 64 + cs * 16);
    }
  }

#define STAGE_B(BUF, CIDX)                                                          \
  do {                                                                              \
    const char* gs_ = Bslice + ((size_t)(CIDX) << 13) + wave * 2048 + lane * 16;    \
    async_lds16((BUF) + wave * 2048, gs_);                                          \
    async_lds16((BUF) + wave * 2048 + 1024, gs_ + 1024);                            \
  } while (0)

  // prime double-buffer: chunks 0 and 1
  STAGE_B(Bs0, 0);
  STAGE_B(Bs1, 1);

  int aoff[4];
#pragma unroll
  for (int i = 0; i < 4; ++i) {
    const int m = wm * 64 + i * 16 + col;
    aoff[i] = m * 64 + ((quad ^ ((m >> 1) & 3)) << 4);
  }

  int qrow[16];
#pragma unroll
  for (int row = 0; row < 16; ++row)
    qrow[row] = mt * 128 + wm * 64 + (row >> 2) * 16 + quad * 4 + (row & 3);

  float vmin[16], thr[16];
#pragma unroll
  for (int row = 0; row < 16; ++row) vmin[row] = 3.4e38f;
  if (PASS == 1) {
#pragma unroll
    for (int row = 0; row < 16; ++row) thr[row] = mono2f(gmin[qrow[row]]) + MARGIN;
  }

  f32x4 acc[4][4];

  __syncthreads();  // full drain once: A tile + B chunks 0,1 landed

  // Per-chunk step. WMODE 2: s_waitcnt vmcnt(2) -- the 2 newest outstanding
  // VMEM ops are this chunk's stage(c+2); everything older (incl. stage(c+1)
  // and any memo stores) is complete. 0: drain. 3: no wait (final chunk).
#define CHUNK(CT, STG, CNEXT, WMODE)                                                \
  do {                                                                              \
    char* Bcur_ = ((CT) & 1) ? Bs1 : Bs0;                                           \
    f16x8 bf_[4], af_[4];                                                           \
    _Pragma("unroll") for (int j = 0; j < 4; ++j)                                   \
        bf_[j] = *(const f16x8*)(Bcur_ + wn * 4096 + j * 1024 + lane * 16);         \
    _Pragma("unroll") for (int i = 0; i < 4; ++i)                                   \
        af_[i] = *(const f16x8*)(Af + (CT) * 8192 + aoff[i]);                       \
    asm volatile("s_waitcnt lgkmcnt(0)" ::: "memory");                              \
    __builtin_amdgcn_sched_barrier(0);                                              \
    __builtin_amdgcn_s_barrier(); /* all waves done reading Bcur_ */                \
    if (STG) {                                                                      \
      STAGE_B(Bcur_, CNEXT);                                                        \
      __builtin_amdgcn_sched_barrier(0); /* keep loads issued before MFMA */        \
    }                                                                               \
    _Pragma("unroll") for (int i = 0; i < 4; ++i)                                   \
        _Pragma("unroll") for (int j = 0; j < 4; ++j)                               \
            acc[i][j] = __builtin_amdgcn_mfma_f32_16x16x32_f16(af_[i], bf_[j],      \
                                                               acc[i][j], 0, 0, 0); \
    if ((WMODE) == 2) {                                                             \
      asm volatile("s_waitcnt vmcnt(2)" ::: "memory");                              \
      __builtin_amdgcn_sched_barrier(0);                                            \
    }                                                                               \
    if ((WMODE) == 0) {                                                             \
      asm volatile("s_waitcnt vmcnt(0)" ::: "memory");                              \
      __builtin_amdgcn_sched_barrier(0);                                            \
    }                                                                               \
    __builtin_amdgcn_s_barrier(); /* next buffer staged for all waves */            \
  } while (0)

#define ZEROACC                                                                     \
  do {                                                                              \
    _Pragma("unroll") for (int i = 0; i < 4; ++i)                                   \
        _Pragma("unroll") for (int j = 0; j < 4; ++j)                               \
            acc[i][j] = (f32x4){0.f, 0.f, 0.f, 0.f};                                \
  } while (0)

#define SCORING(NT)                                                                 \
  do {                                                                              \
    const int k0_ = (slice * 8 + (NT)) * 128;                                       \
    float cn_[4];                                                                   \
    _Pragma("unroll") for (int j = 0; j < 4; ++j)                                   \
        cn_[j] = cbnorm[k0_ + wn * 64 + j * 16 + col];                              \
    unsigned* sb_ = (PASS == 3)                                                     \
        ? memo + ((((unsigned)blockIdx.x * 8u + (unsigned)(NT)) * 4u +              \
                   (unsigned)wave) * 8u) * 64u + (unsigned)lane                     \
        : nullptr;                                                                  \
    float prev_ = 0.f;                                                              \
    _Pragma("unroll") for (int i = 0; i < 4; ++i)                                   \
        _Pragma("unroll") for (int r = 0; r < 4; ++r) {                             \
      const int row_ = i * 4 + r;                                                   \
      const float s0_ = __builtin_fmaf(acc[i][0][r], KSC, cn_[0]);                  \
      const float s1_ = __builtin_fmaf(acc[i][1][r], KSC, cn_[1]);                  \
      const float s2_ = __builtin_fmaf(acc[i][2][r], KSC, cn_[2]);                  \
      const float s3_ = __builtin_fmaf(acc[i][3][r], KSC, cn_[3]);                  \
      const float rm_ = fminf(fminf(s0_, s1_), fminf(s2_, s3_));                    \
      if (PASS != 1) {                                                              \
        vmin[row_] = fminf(vmin[row_], rm_);                                        \
        if (PASS == 3) {                                                            \
          if ((r & 1) == 0) prev_ = rm_;                                            \
          else sb_[(unsigned)((i * 2 + (r >> 1)) * 64)] = pack_f16x2(prev_, rm_);   \
        }                                                                           \
      } else if (rm_ <= thr[row_]) { /* exact early-out: min_j > thr => none */     \
        const float sv_[4] = {s0_, s1_, s2_, s3_};                                  \
        _Pragma("unroll") for (int j = 0; j < 4; ++j) {                             \
          if (sv_[j] <= thr[row_]) {                                                \
            const int slot_ = atomicAdd(paircount, 1);                              \
            if (slot_ < CAP_PAIRS)                                                  \
              pairs[slot_] = ((unsigned)qrow[row_] << 13) |                         \
                             (unsigned)(k0_ + wn * 64 + j * 16 + col);              \
          }                                                                         \
        }                                                                           \
      }                                                                             \
    }                                                                               \
  } while (0)

  for (int nt = 0; nt < 7; ++nt) {
    ZEROACC;
#pragma unroll
    for (int ct = 0; ct < 8; ++ct) CHUNK(ct, true, nt * 8 + ct + 2, 2);
    SCORING(nt);
  }
  // nt = 7 epilogue: stop staging at chunk 63, then drain
  ZEROACC;
  CHUNK(0, true, 58, 2);
  CHUNK(1, true, 59, 2);
  CHUNK(2, true, 60, 2);
  CHUNK(3, true, 61, 2);
  CHUNK(4, true, 62, 2);
  CHUNK(5, true, 63, 2);
  CHUNK(6, false, 0, 0);
  CHUNK(7, false, 0, 3);
  SCORING(7);

#undef STAGE_B
#undef CHUNK
#undef ZEROACC
#undef SCORING

  if (PASS != 1) {
    // cross-col min (value only), then atomicMin per row
#pragma unroll
    for (int row = 0; row < 16; ++row) {
      float v = vmin[row];
      v = fminf(v, __shfl_xor(v, 1, 64));
      v = fminf(v, __shfl_xor(v, 2, 64));
      v = fminf(v, __shfl_xor(v, 4, 64));
      v = fminf(v, __shfl_xor(v, 8, 64));
      if (col == 0) atomicMin(&gmin[qrow[row]], f2mono(v));
    }
  }
}

__global__ __launch_bounds__(256, 2) void gemm_pass1(const char* __restrict__ At,
                                                     const char* __restrict__ Bt,
                                                     const float* __restrict__ cbnorm,
                                                     unsigned* __restrict__ gmin) {
  gemm_body<0>(At, Bt, cbnorm, gmin, nullptr, nullptr, nullptr);
}

__global__ __launch_bounds__(256, 2) void gemm_pass1m(const char* __restrict__ At,
                                                      const char* __restrict__ Bt,
                                                      const float* __restrict__ cbnorm,
                                                      unsigned* __restrict__ gmin,
                                                      unsigned* __restrict__ memo) {
  gemm_body<3>(At, Bt, cbnorm, gmin, nullptr, nullptr, memo);
}

__global__ __launch_bounds__(256, 2) void gemm_pass2(const char* __restrict__ At,
                                                     const char* __restrict__ Bt,
                                                     const float* __restrict__ cbnorm,
                                                     unsigned* __restrict__ gmin,
                                                     unsigned* __restrict__ pairs,
                                                     int* __restrict__ paircount) {
  gemm_body<1>(At, Bt, cbnorm, gmin, pairs, paircount, nullptr);
}

// ---------------------------------------------------------------------------
// scan_rm: stream the 64 MiB fp16 group-min memo; push group id for every
// stored rm <= gmin[q] + MARGIN + RM_ERR. Group = (q, ntile, wn, col) = 4 k's.
// Superset of candidate groups (rm <= a(k) for any k in group, stored err
// <= RM_ERR); exact4's fp32 rescore picks the identical winner.
// id encoding: (q << 11) | (ntile << 5) | (wn << 4) | col.
// ---------------------------------------------------------------------------
__global__ __launch_bounds__(256) void scan_rm(const unsigned* __restrict__ memo,
                                               const unsigned* __restrict__ gmin,
                                               unsigned* __restrict__ pairs,
                                               int* __restrict__ paircount) {
  const unsigned NU4 = 4194304u;  // 64 MiB / 16
  const unsigned stride = gridDim.x * blockDim.x;
  for (unsigned U = blockIdx.x * 256 + threadIdx.x; U < NU4; U += stride) {
    const uint4 v = ((const uint4*)memo)[U];
    const unsigned u = U << 2;
    const unsigned lane0 = u & 63, col0 = lane0 & 15, quad = lane0 >> 4;
    const unsigned rp = (u >> 6) & 7;
    const unsigned w = (u >> 9) & 3;
    const unsigned t = (u >> 11) & 7;
    const unsigned blk = u >> 14;
    const unsigned mt = blk >> 3, slice = blk & 7;
    const unsigned wm = w >> 1, wn = w & 1;
    const unsigned ntile = slice * 8u + t;
    const unsigned row0 = rp * 2u;
    const int q0 = (int)(mt * 128u + wm * 64u + (row0 >> 2) * 16u + quad * 4u + (row0 & 3u));
    const float thr0 = mono2f(gmin[q0]) + (MARGIN + RM_ERR);
    const float thr1 = mono2f(gmin[q0 + 1]) + (MARGIN + RM_ERR);
    const unsigned wv[4] = {v.x, v.y, v.z, v.w};
#pragma unroll
    for (int wi = 0; wi < 4; ++wi) {
      const unsigned kid = (ntile << 5) | (wn << 4) | (col0 + (unsigned)wi);
      const float lo = (float)__builtin_bit_cast(_Float16, (unsigned short)(wv[wi] & 0xffffu));
      const float hi = (float)__builtin_bit_cast(_Float16, (unsigned short)(wv[wi] >> 16));
      if (lo <= thr0) {
        const int slot = atomicAdd(paircount, 1);
        if (slot < CAP_PAIRS) pairs[slot] = ((unsigned)q0 << 11) | kid;
      }
      if (hi <= thr1) {
        const int slot = atomicAdd(paircount, 1);
        if (slot < CAP_PAIRS) pairs[slot] = ((unsigned)(q0 + 1) << 11) | kid;
      }
    }
  }
}

// ---------------------------------------------------------------------------
// exact4: fp32 rescore of all 4 k's of each pushed group (np chain,
// R4-verified machinery, identical op order to exact_cand). One wave per
// group; per-q winner via packed atomicMin (ties -> min k).
// ---------------------------------------------------------------------------
__global__ __launch_bounds__(256) void exact4(const float* __restrict__ zT,
                                              const float* __restrict__ cb,
                                              const float* __restrict__ cbnorm,
                                              const float* __restrict__ znorm,
                                              const unsigned* __restrict__ pairs,
                                              const int* __restrict__ paircount,
                                              unsigned long long* __restrict__ packed) {
  const int cnt = min(*paircount, CAP_PAIRS);
  const int gw = (blockIdx.x * 256 + threadIdx.x) >> 6;
  const int nw = (gridDim.x * 256) >> 6;
  const int lane = threadIdx.x & 63;
  for (int p = gw; p < cnt; p += nw) {
    const unsigned id = pairs[p];
    const int q = (int)(id >> 11);
    const int base = (int)(((id >> 5) & 63u) * 128u + ((id >> 4) & 1u) * 64u + (id & 15u));
    const float4 zv = ((const float4*)(zT + (size_t)q * FEAT))[lane];
    const float zn = znorm[q];
    unsigned long long best = ~0ull;
#pragma unroll
    for (int j = 0; j < 4; ++j) {
      const int k = base + j * 16;
      const float4 cv = ((const float4*)(cb + (size_t)k * FEAT))[lane];
      float d = __builtin_fmaf(zv.w, cv.w,
                __builtin_fmaf(zv.z, cv.z,
                __builtin_fmaf(zv.y, cv.y, __fmul_rn(zv.x, cv.x))));
#pragma unroll
      for (int dd = 1; dd < 64; dd <<= 1) d = __fadd_rn(d, __shfl_xor(d, dd, 64));
      const float s = __fadd_rn(__fadd_rn(__fmul_rn(-2.0f, d), zn), cbnorm[k]);
      const unsigned long long key = ((unsigned long long)f2mono(s) << 32) | (unsigned)k;
      best = (key < best) ? key : best;
    }
    if (lane == 0) atomicMin(&packed[q], best);
  }
}

// ---------------------------------------------------------------------------
// Exact fp32 rescore of (q,k) pairs (fallback path, R4-verified machinery).
// ---------------------------------------------------------------------------
__global__ __launch_bounds__(256) void exact_cand(const float* __restrict__ zT,
                                                  const float* __restrict__ cb,
                                                  const float* __restrict__ cbnorm,
                                                  const float* __restrict__ znorm,
                                                  const unsigned* __restrict__ pairs,
                                                  const int* __restrict__ paircount,
                                                  unsigned long long* __restrict__ packed) {
  const int cnt = min(*paircount, CAP_PAIRS);
  const int gw = (blockIdx.x * 256 + threadIdx.x) >> 6;
  const int nw = (gridDim.x * 256) >> 6;
  const int lane = threadIdx.x & 63;
  for (int p = gw; p < cnt; p += nw) {
    const unsigned qk = pairs[p];
    const int q = qk >> 13, k = qk & 8191;
    const float4 cv = ((const float4*)(cb + (size_t)k * FEAT))[lane];
    const float4 zv = ((const float4*)(zT + (size_t)q * FEAT))[lane];
    float d = __builtin_fmaf(zv.w, cv.w,
              __builtin_fmaf(zv.z, cv.z,
              __builtin_fmaf(zv.y, cv.y, __fmul_rn(zv.x, cv.x))));
#pragma unroll
    for (int dd = 1; dd < 64; dd <<= 1) d = __fadd_rn(d, __shfl_xor(d, dd, 64));
    const float s = __fadd_rn(__fadd_rn(__fmul_rn(-2.0f, d), znorm[q]), cbnorm[k]);
    if (lane == 0) {
      const unsigned long long key = ((unsigned long long)f2mono(s) << 32) | (unsigned)k;
      atomicMin(&packed[q], key);
    }
  }
}

// ---------------------------------------------------------------------------
// Gather: zq[b][c][hw] = cb[idx]; idx as float appended after zq.
// ---------------------------------------------------------------------------
__global__ __launch_bounds__(256) void vq_gather(const float* __restrict__ cb,
                                                 const unsigned long long* __restrict__ packed,
                                                 float* __restrict__ out) {
  const int q0 = blockIdx.x * 64;
  const int nl = threadIdx.x & 63;
  const int cg = threadIdx.x >> 6;
  const int q = q0 + nl;
  const int kq = (int)((unsigned)packed[q] & 8191u);
  const int b = q >> 10, hw = q & 1023;
  const float4* cb4 = (const float4*)cb;
#pragma unroll
  for (int t = 0; t < 16; ++t) {
    const int cc = cg + t * 4;
    const float4 v = cb4[kq * 64 + cc];
    const int base = b * (FEAT * 1024) + (cc * 4) * 1024 + hw;
    out[base] = v.x;
    out[base + 1024] = v.y;
    out[base + 2048] = v.z;
    out[base + 3072] = v.w;
  }
  if (threadIdx.x < 64) {
    const int qq = q0 + threadIdx.x;
    out[ZQ_ELEMS + qq] = (float)(int)((unsigned)packed[qq] & 8191u);
  }
}

extern "C" void kernel_launch(void* const* d_in, const int* in_sizes, int n_in,
                              void* d_out, int out_size, void* d_ws, size_t ws_size,
                              hipStream_t stream) {
  const float* z = (const float*)d_in[0];
  const float* cb = (const float*)d_in[1];
  char* w = (char*)d_ws;
  // ws layout: ~30 MiB fixed + 64 MiB group-min memo at MEMO_OFF
  char* At = w;                                            // 8 MB
  char* Bt = w + 8388608;                                  // 4 MB
  float* zT = (float*)(w + 12582912);                      // 16 MB
  float* cbnorm = (float*)(w + 29360128);                  // 32 KB
  float* znorm = (float*)(w + 29392896);                   // 64 KB
  unsigned* gmin = (unsigned*)(w + 29458432);              // 64 KB
  int* paircount = (int*)(w + 29523968);                   // 256 B
  unsigned* pairs = (unsigned*)(w + 29524224);             // 1 MB (256K entries)
  unsigned long long* packed = (unsigned long long*)(w + 30572800);  // 128 KB
  unsigned* memo = (unsigned*)(w + MEMO_OFF);              // 64 MiB fp16 group-mins

  const bool use_memo =
      ws_size >= (size_t)(MEMO_OFF + MEMO_BYTES);

  hipMemsetAsync(paircount, 0, 256, stream);
  hipMemsetAsync(gmin, 0xFF, NQ * sizeof(unsigned), stream);
  hipMemsetAsync(packed, 0xFF, NQ * sizeof(unsigned long long), stream);
  norms_kernel<<<(CODES + NQ) / 16, 256, 0, stream>>>(cb, z, cbnorm, znorm);
  convA<<<1024, 256, 0, stream>>>(z, At, zT);
  convB<<<512, 256, 0, stream>>>(cb, Bt);
  if (use_memo) {
    gemm_pass1m<<<(NQ / 128) * NSLICE, 256, 0, stream>>>(At, Bt, cbnorm, gmin, memo);
    scan_rm<<<2048, 256, 0, stream>>>(memo, gmin, pairs, paircount);
    exact4<<<512, 256, 0, stream>>>(zT, cb, cbnorm, znorm, pairs, paircount, packed);
  } else {
    gemm_pass1<<<(NQ / 128) * NSLICE, 256, 0, stream>>>(At, Bt, cbnorm, gmin);
    gemm_pass2<<<(NQ / 128) * NSLICE, 256, 0, stream>>>(At, Bt, cbnorm, gmin, pairs, paircount);
    exact_cand<<<512, 256, 0, stream>>>(zT, cb, cbnorm, znorm, pairs, paircount, packed);
  }
  vq_gather<<<NQ / 64, 256, 0, stream>>>(cb, packed, (float*)d_out);
}

// Round 9
// 230.936 us; speedup vs baseline: 3.3719x; 1.7621x over previous
//
#include <hip/hip_runtime.h>
#include <stdint.h>

#define FEAT 256
#define CODES 8192
#define NQ 16384                 // 16*32*32
#define ZQ_ELEMS (NQ * FEAT)
#define MARGIN 2e-3f             // = 2e bound on fp16 score error (R4-validated)
#define RM_ERR 1.0e-3f           // fp16 RNE storage err bound for |rm| < 2
#define NSLICE 8
#define CAP_PAIRS (1 << 18)      // 256K (expected ~20K groups)
#define KSC (-0.0078125f)        // descale: acc * -2/256
#define MEMO_OFF 31457280ull     // 30 MiB: right after fixed ws region
#define MEMO_BYTES 67108864ull   // 64 MiB fp16 group-mins
#define LBUF_N 1024              // per-block candidate buffer (expected ~9 hits)

typedef _Float16 f16x8 __attribute__((ext_vector_type(8)));
typedef float f32x4 __attribute__((ext_vector_type(4)));

__device__ __forceinline__ void async_lds16(void* lds, const void* g) {
  __builtin_amdgcn_global_load_lds(
      (const __attribute__((address_space(1))) void*)(uintptr_t)(g),
      (__attribute__((address_space(3))) void*)(uint32_t)(uintptr_t)(lds),
      16, 0, 0);
}

// monotone float<->uint order transform
__device__ __forceinline__ unsigned f2mono(float v) {
  unsigned u = __float_as_uint(v);
  return (u & 0x80000000u) ? ~u : (u | 0x80000000u);
}
__device__ __forceinline__ float mono2f(unsigned t) {
  unsigned u = (t & 0x80000000u) ? (t & 0x7fffffffu) : ~t;
  return __uint_as_float(u);
}
__device__ __forceinline__ unsigned pack_f16x2(float a, float b) {
  unsigned short ha = __builtin_bit_cast(unsigned short, (_Float16)a);
  unsigned short hb = __builtin_bit_cast(unsigned short, (_Float16)b);
  return (unsigned)ha | ((unsigned)hb << 16);
}

// ---------------------------------------------------------------------------
// numpy pairwise sum-of-squares replication (verified R1-R4, absmax 0).
// ---------------------------------------------------------------------------
template <int STRIDE>
__device__ __forceinline__ float pairwise256_sq(const float* __restrict__ base, int lane16) {
  const int h = lane16 >> 3, j = lane16 & 7;
  const float* p = base + (h * 128 + j) * STRIDE;
  float x = p[0];
  float r = __fmul_rn(x, x);
#pragma unroll
  for (int i = 1; i < 16; ++i) {
    float y = p[i * 8 * STRIDE];
    r = __fadd_rn(r, __fmul_rn(y, y));
  }
  r = __fadd_rn(r, __shfl_xor(r, 1, 64));
  r = __fadd_rn(r, __shfl_xor(r, 2, 64));
  r = __fadd_rn(r, __shfl_xor(r, 4, 64));
  float other = __shfl_xor(r, 8, 64);
  float lo = (h == 0) ? r : other;
  float hi = (h == 0) ? other : r;
  return __fadd_rn(lo, hi);
}

__global__ __launch_bounds__(256) void norms_kernel(const float* __restrict__ cb,
                                                    const float* __restrict__ z,
                                                    float* __restrict__ cbnorm,
                                                    float* __restrict__ znorm) {
  const int g = (blockIdx.x * 256 + threadIdx.x) >> 4;
  const int lane16 = threadIdx.x & 15;
  if (g < CODES) {
    float v = pairwise256_sq<1>(cb + g * FEAT, lane16);
    if (lane16 == 0) cbnorm[g] = v;
  } else {
    const int q = g - CODES;
    const int b = q >> 10, hw = q & 1023;
    float v = pairwise256_sq<1024>(z + b * (FEAT * 1024) + hw, lane16);
    if (lane16 == 0) znorm[q] = v;
  }
}

// ---------------------------------------------------------------------------
// convA: z fp32 -> fp16 tiles [mt][ct][r128][c32] + fp32 transpose zT[q][c]
// ---------------------------------------------------------------------------
__global__ __launch_bounds__(256) void convA(const float* __restrict__ z,
                                             char* __restrict__ At, float* __restrict__ zT) {
  __shared__ _Float16 T[128 * 40];
  __shared__ float Tf[128 * 36];
  const int t = threadIdx.x;
  const int mt = blockIdx.x >> 3, ct = blockIdx.x & 7;
  const int q0 = mt * 128, bb = q0 >> 10, hw0 = q0 & 1023;
  const int c0 = ct * 32;
#pragma unroll
  for (int it = 0; it < 16; ++it) {
    const int cc = it * 2 + (t >> 7);
    const int qi = t & 127;
    float v = z[bb * (FEAT * 1024) + (c0 + cc) * 1024 + hw0 + qi];
    T[qi * 40 + cc] = (_Float16)v;
    Tf[qi * 36 + cc] = v;
  }
  __syncthreads();
  const int r = t >> 1, h = t & 1;
  {
    float4 a = *(const float4*)&T[r * 40 + h * 16];
    float4 b = *(const float4*)&T[r * 40 + h * 16 + 8];
    char* dst = At + (size_t)(mt * 8 + ct) * 8192 + t * 32;
    *(float4*)dst = a;
    *(float4*)(dst + 16) = b;
  }
  float* zrow = zT + (size_t)(q0 + r) * FEAT + c0 + h * 16;
#pragma unroll
  for (int e = 0; e < 4; ++e)
    *(float4*)(zrow + e * 4) = *(const float4*)&Tf[r * 36 + h * 16 + e * 4];
}

// ---------------------------------------------------------------------------
// convB: cb fp32 -> fp16 FRAGMENT-LINEAR layout, scaled by 256.
// Verified absmax 0 in R1/R2/R4/R5/R7/R8.
// ---------------------------------------------------------------------------
__global__ __launch_bounds__(256) void convB(const float* __restrict__ cb, char* __restrict__ Bt) {
  const int T = blockIdx.x * 256 + threadIdx.x;   // [0, 131072)
  const int K = T >> 4, part = T & 15;            // K: code row; part: 16-float chunk
  const float* src = cb + (size_t)K * FEAT + part * 16;
  const int nt = K >> 7, rem = K & 127;
  const int wn = rem >> 6, j = (rem >> 4) & 3, llo = rem & 15;
#pragma unroll
  for (int g = 0; g < 2; ++g) {
    const int c0 = part * 16 + g * 8;
    const int ct = c0 >> 5, lhi = (c0 >> 3) & 3;
    const int cg = nt * 8 + ct;
    f16x8 o;
#pragma unroll
    for (int e = 0; e < 8; ++e) o[e] = (_Float16)(src[g * 8 + e] * 256.0f);
    const size_t s = ((size_t)((cg * 2 + wn) * 4 + j) << 6) + (size_t)(lhi * 16 + llo);
    *(f16x8*)(Bt + s * 16) = o;
  }
}

// ---------------------------------------------------------------------------
// Shared GEMM body, R2-proven structure: A-tile (64 KB, all K) resident in
// LDS; B chunks (8 KB) double-buffered via global_load_lds, counted vmcnt(2)
// waits, raw s_barriers, sched_barrier(0) fences.
// PASS=0: per-row running min -> atomicMin gmin[q].
// PASS=1: (fallback pass2) push (q<<13|k) for score <= gmin[q]+MARGIN.
// PASS=3: PASS0 + store per-(row,tile) 4-k group-min rm_ as packed fp16x2.
//         memo layout (uints): ((((blk*8+nt)*4+wave)*8)+rp)*64 + lane,
//         uint = f16x2(rm[2rp], rm[2rp+1]). 64 MiB total.
// ---------------------------------------------------------------------------
template <int PASS>
__device__ __forceinline__ void gemm_body(const char* __restrict__ At,
                                          const char* __restrict__ Bt,
                                          const float* __restrict__ cbnorm,
                                          unsigned* __restrict__ gmin,
                                          unsigned* __restrict__ pairs,
                                          int* __restrict__ paircount,
                                          unsigned* __restrict__ memo) {
  __shared__ __align__(16) char Af[65536];
  __shared__ __align__(16) char Bs0[8192];
  __shared__ __align__(16) char Bs1[8192];

  const int tid = threadIdx.x;
  const int slice = blockIdx.x & 7, mt = blockIdx.x >> 3;
  const int wave = tid >> 6, lane = tid & 63;
  const int wm = wave >> 1, wn = wave & 1;
  const int col = lane & 15, quad = lane >> 4;

  const int srow = wave * 32 + (lane >> 2);  // A staging row within 32-row group
  const int ss = lane & 3;
  const char* Abase = At + (size_t)(mt * 8) * 8192;
  const char* Bslice = Bt + (size_t)slice * 524288;

  // stage entire A tile (8 ct-chunks) into LDS, swizzled slots
#pragma unroll
  for (int ct = 0; ct < 8; ++ct) {
#pragma unroll
    for (int i = 0; i < 2; ++i) {
      const int r = srow + i * 16;
      const int cs = ss ^ ((r >> 1) & 3);
      async_lds16(Af + ct * 8192 + wave * 2048 + i * 1024,
                  Abase + (size_t)ct * 8192 + r * 64 + cs * 16);
    }
  }

#define STAGE_B(BUF, CIDX)                                                          \
  do {                                                                              \
    const char* gs_ = Bslice + ((size_t)(CIDX) << 13) + wave * 2048 + lane * 16;    \
    async_lds16((BUF) + wave * 2048, gs_);                                          \
    async_lds16((BUF) + wave * 2048 + 1024, gs_ + 1024);                            \
  } while (0)

  // prime double-buffer: chunks 0 and 1
  STAGE_B(Bs0, 0);
  STAGE_B(Bs1, 1);

  int aoff[4];
#pragma unroll
  for (int i = 0; i < 4; ++i) {
    const int m = wm * 64 + i * 16 + col;
    aoff[i] = m * 64 + ((quad ^ ((m >> 1) & 3)) << 4);
  }

  int qrow[16];
#pragma unroll
  for (int row = 0; row < 16; ++row)
    qrow[row] = mt * 128 + wm * 64 + (row >> 2) * 16 + quad * 4 + (row & 3);

  float vmin[16], thr[16];
#pragma unroll
  for (int row = 0; row < 16; ++row) vmin[row] = 3.4e38f;
  if (PASS == 1) {
#pragma unroll
    for (int row = 0; row < 16; ++row) thr[row] = mono2f(gmin[qrow[row]]) + MARGIN;
  }

  f32x4 acc[4][4];

  __syncthreads();  // full drain once: A tile + B chunks 0,1 landed

  // Per-chunk step. WMODE 2: s_waitcnt vmcnt(2) -- the 2 newest outstanding
  // VMEM ops are this chunk's stage(c+2); everything older (incl. stage(c+1)
  // and any memo stores) is complete. 0: drain. 3: no wait (final chunk).
#define CHUNK(CT, STG, CNEXT, WMODE)                                                \
  do {                                                                              \
    char* Bcur_ = ((CT) & 1) ? Bs1 : Bs0;                                           \
    f16x8 bf_[4], af_[4];                                                           \
    _Pragma("unroll") for (int j = 0; j < 4; ++j)                                   \
        bf_[j] = *(const f16x8*)(Bcur_ + wn * 4096 + j * 1024 + lane * 16);         \
    _Pragma("unroll") for (int i = 0; i < 4; ++i)                                   \
        af_[i] = *(const f16x8*)(Af + (CT) * 8192 + aoff[i]);                       \
    asm volatile("s_waitcnt lgkmcnt(0)" ::: "memory");                              \
    __builtin_amdgcn_sched_barrier(0);                                              \
    __builtin_amdgcn_s_barrier(); /* all waves done reading Bcur_ */                \
    if (STG) {                                                                      \
      STAGE_B(Bcur_, CNEXT);                                                        \
      __builtin_amdgcn_sched_barrier(0); /* keep loads issued before MFMA */        \
    }                                                                               \
    _Pragma("unroll") for (int i = 0; i < 4; ++i)                                   \
        _Pragma("unroll") for (int j = 0; j < 4; ++j)                               \
            acc[i][j] = __builtin_amdgcn_mfma_f32_16x16x32_f16(af_[i], bf_[j],      \
                                                               acc[i][j], 0, 0, 0); \
    if ((WMODE) == 2) {                                                             \
      asm volatile("s_waitcnt vmcnt(2)" ::: "memory");                              \
      __builtin_amdgcn_sched_barrier(0);                                            \
    }                                                                               \
    if ((WMODE) == 0) {                                                             \
      asm volatile("s_waitcnt vmcnt(0)" ::: "memory");                              \
      __builtin_amdgcn_sched_barrier(0);                                            \
    }                                                                               \
    __builtin_amdgcn_s_barrier(); /* next buffer staged for all waves */            \
  } while (0)

#define ZEROACC                                                                     \
  do {                                                                              \
    _Pragma("unroll") for (int i = 0; i < 4; ++i)                                   \
        _Pragma("unroll") for (int j = 0; j < 4; ++j)                               \
            acc[i][j] = (f32x4){0.f, 0.f, 0.f, 0.f};                                \
  } while (0)

#define SCORING(NT)                                                                 \
  do {                                                                              \
    const int k0_ = (slice * 8 + (NT)) * 128;                                       \
    float cn_[4];                                                                   \
    _Pragma("unroll") for (int j = 0; j < 4; ++j)                                   \
        cn_[j] = cbnorm[k0_ + wn * 64 + j * 16 + col];                              \
    unsigned* sb_ = (PASS == 3)                                                     \
        ? memo + ((((unsigned)blockIdx.x * 8u + (unsigned)(NT)) * 4u +              \
                   (unsigned)wave) * 8u) * 64u + (unsigned)lane                     \
        : nullptr;                                                                  \
    float prev_ = 0.f;                                                              \
    _Pragma("unroll") for (int i = 0; i < 4; ++i)                                   \
        _Pragma("unroll") for (int r = 0; r < 4; ++r) {                             \
      const int row_ = i * 4 + r;                                                   \
      const float s0_ = __builtin_fmaf(acc[i][0][r], KSC, cn_[0]);                  \
      const float s1_ = __builtin_fmaf(acc[i][1][r], KSC, cn_[1]);                  \
      const float s2_ = __builtin_fmaf(acc[i][2][r], KSC, cn_[2]);                  \
      const float s3_ = __builtin_fmaf(acc[i][3][r], KSC, cn_[3]);                  \
      const float rm_ = fminf(fminf(s0_, s1_), fminf(s2_, s3_));                    \
      if (PASS != 1) {                                                              \
        vmin[row_] = fminf(vmin[row_], rm_);                                        \
        if (PASS == 3) {                                                            \
          if ((r & 1) == 0) prev_ = rm_;                                            \
          else sb_[(unsigned)((i * 2 + (r >> 1)) * 64)] = pack_f16x2(prev_, rm_);   \
        }                                                                           \
      } else if (rm_ <= thr[row_]) { /* exact early-out: min_j > thr => none */     \
        const float sv_[4] = {s0_, s1_, s2_, s3_};                                  \
        _Pragma("unroll") for (int j = 0; j < 4; ++j) {                             \
          if (sv_[j] <= thr[row_]) {                                                \
            const int slot_ = atomicAdd(paircount, 1);                              \
            if (slot_ < CAP_PAIRS)                                                  \
              pairs[slot_] = ((unsigned)qrow[row_] << 13) |                         \
                             (unsigned)(k0_ + wn * 64 + j * 16 + col);              \
          }                                                                         \
        }                                                                           \
      }                                                                             \
    }                                                                               \
  } while (0)

  for (int nt = 0; nt < 7; ++nt) {
    ZEROACC;
#pragma unroll
    for (int ct = 0; ct < 8; ++ct) CHUNK(ct, true, nt * 8 + ct + 2, 2);
    SCORING(nt);
  }
  // nt = 7 epilogue: stop staging at chunk 63, then drain
  ZEROACC;
  CHUNK(0, true, 58, 2);
  CHUNK(1, true, 59, 2);
  CHUNK(2, true, 60, 2);
  CHUNK(3, true, 61, 2);
  CHUNK(4, true, 62, 2);
  CHUNK(5, true, 63, 2);
  CHUNK(6, false, 0, 0);
  CHUNK(7, false, 0, 3);
  SCORING(7);

#undef STAGE_B
#undef CHUNK
#undef ZEROACC
#undef SCORING

  if (PASS != 1) {
    // cross-col min (value only), then atomicMin per row
#pragma unroll
    for (int row = 0; row < 16; ++row) {
      float v = vmin[row];
      v = fminf(v, __shfl_xor(v, 1, 64));
      v = fminf(v, __shfl_xor(v, 2, 64));
      v = fminf(v, __shfl_xor(v, 4, 64));
      v = fminf(v, __shfl_xor(v, 8, 64));
      if (col == 0) atomicMin(&gmin[qrow[row]], f2mono(v));
    }
  }
}

__global__ __launch_bounds__(256, 2) void gemm_pass1(const char* __restrict__ At,
                                                     const char* __restrict__ Bt,
                                                     const float* __restrict__ cbnorm,
                                                     unsigned* __restrict__ gmin) {
  gemm_body<0>(At, Bt, cbnorm, gmin, nullptr, nullptr, nullptr);
}

__global__ __launch_bounds__(256, 2) void gemm_pass1m(const char* __restrict__ At,
                                                      const char* __restrict__ Bt,
                                                      const float* __restrict__ cbnorm,
                                                      unsigned* __restrict__ gmin,
                                                      unsigned* __restrict__ memo) {
  gemm_body<3>(At, Bt, cbnorm, gmin, nullptr, nullptr, memo);
}

__global__ __launch_bounds__(256, 2) void gemm_pass2(const char* __restrict__ At,
                                                     const char* __restrict__ Bt,
                                                     const float* __restrict__ cbnorm,
                                                     unsigned* __restrict__ gmin,
                                                     unsigned* __restrict__ pairs,
                                                     int* __restrict__ paircount) {
  gemm_body<1>(At, Bt, cbnorm, gmin, pairs, paircount, nullptr);
}

// ---------------------------------------------------------------------------
// scan_rm: stream the 64 MiB fp16 group-min memo; collect hits in a per-block
// LDS buffer (LDS atomics only -- no global hot-line), then ONE global
// atomicAdd per block reserves a slot range and the buffer is flushed
// coalesced. Overflow (>LBUF_N hits/block, ~impossible for random data)
// falls back to direct global push -- superset property preserved in all
// cases; exact4's fp32 rescore picks the identical winner.
// id encoding: (q << 11) | (ntile << 5) | (wn << 4) | col.
// ---------------------------------------------------------------------------
__global__ __launch_bounds__(256) void scan_rm(const unsigned* __restrict__ memo,
                                               const unsigned* __restrict__ gmin,
                                               unsigned* __restrict__ pairs,
                                               int* __restrict__ paircount) {
  __shared__ unsigned lbuf[LBUF_N];
  __shared__ int lcnt, gbase;
  if (threadIdx.x == 0) lcnt = 0;
  __syncthreads();

  const unsigned NU4 = 4194304u;  // 64 MiB / 16
  const unsigned stride = gridDim.x * blockDim.x;
  for (unsigned U = blockIdx.x * 256 + threadIdx.x; U < NU4; U += stride) {
    const uint4 v = ((const uint4*)memo)[U];
    const unsigned u = U << 2;
    const unsigned lane0 = u & 63, col0 = lane0 & 15, quad = lane0 >> 4;
    const unsigned rp = (u >> 6) & 7;
    const unsigned w = (u >> 9) & 3;
    const unsigned t = (u >> 11) & 7;
    const unsigned blk = u >> 14;
    const unsigned mt = blk >> 3, slice = blk & 7;
    const unsigned wm = w >> 1, wn = w & 1;
    const unsigned ntile = slice * 8u + t;
    const unsigned row0 = rp * 2u;
    const int q0 = (int)(mt * 128u + wm * 64u + (row0 >> 2) * 16u + quad * 4u + (row0 & 3u));
    const float thr0 = mono2f(gmin[q0]) + (MARGIN + RM_ERR);
    const float thr1 = mono2f(gmin[q0 + 1]) + (MARGIN + RM_ERR);
    const unsigned wv[4] = {v.x, v.y, v.z, v.w};
#pragma unroll
    for (int wi = 0; wi < 4; ++wi) {
      const unsigned kid = (ntile << 5) | (wn << 4) | (col0 + (unsigned)wi);
      const float lo = (float)__builtin_bit_cast(_Float16, (unsigned short)(wv[wi] & 0xffffu));
      const float hi = (float)__builtin_bit_cast(_Float16, (unsigned short)(wv[wi] >> 16));
      if (lo <= thr0) {
        const unsigned id = ((unsigned)q0 << 11) | kid;
        const int idx = atomicAdd(&lcnt, 1);
        if (idx < LBUF_N) {
          lbuf[idx] = id;
        } else {
          const int slot = atomicAdd(paircount, 1);
          if (slot < CAP_PAIRS) pairs[slot] = id;
        }
      }
      if (hi <= thr1) {
        const unsigned id = ((unsigned)(q0 + 1) << 11) | kid;
        const int idx = atomicAdd(&lcnt, 1);
        if (idx < LBUF_N) {
          lbuf[idx] = id;
        } else {
          const int slot = atomicAdd(paircount, 1);
          if (slot < CAP_PAIRS) pairs[slot] = id;
        }
      }
    }
  }

  __syncthreads();
  const int n = min(lcnt, LBUF_N);
  if (threadIdx.x == 0) gbase = atomicAdd(paircount, n);
  __syncthreads();
  for (int i = threadIdx.x; i < n; i += 256) {
    const int slot = gbase + i;
    if (slot < CAP_PAIRS) pairs[slot] = lbuf[i];
  }
}

// ---------------------------------------------------------------------------
// exact4: fp32 rescore of all 4 k's of each pushed group (np chain,
// R4-verified machinery, identical op order to exact_cand). One wave per
// group; per-q winner via packed atomicMin (ties -> min k).
// ---------------------------------------------------------------------------
__global__ __launch_bounds__(256) void exact4(const float* __restrict__ zT,
                                              const float* __restrict__ cb,
                                              const float* __restrict__ cbnorm,
                                              const float* __restrict__ znorm,
                                              const unsigned* __restrict__ pairs,
                                              const int* __restrict__ paircount,
                                              unsigned long long* __restrict__ packed) {
  const int cnt = min(*paircount, CAP_PAIRS);
  const int gw = (blockIdx.x * 256 + threadIdx.x) >> 6;
  const int nw = (gridDim.x * 256) >> 6;
  const int lane = threadIdx.x & 63;
  for (int p = gw; p < cnt; p += nw) {
    const unsigned id = pairs[p];
    const int q = (int)(id >> 11);
    const int base = (int)(((id >> 5) & 63u) * 128u + ((id >> 4) & 1u) * 64u + (id & 15u));
    const float4 zv = ((const float4*)(zT + (size_t)q * FEAT))[lane];
    const float zn = znorm[q];
    unsigned long long best = ~0ull;
#pragma unroll
    for (int j = 0; j < 4; ++j) {
      const int k = base + j * 16;
      const float4 cv = ((const float4*)(cb + (size_t)k * FEAT))[lane];
      float d = __builtin_fmaf(zv.w, cv.w,
                __builtin_fmaf(zv.z, cv.z,
                __builtin_fmaf(zv.y, cv.y, __fmul_rn(zv.x, cv.x))));
#pragma unroll
      for (int dd = 1; dd < 64; dd <<= 1) d = __fadd_rn(d, __shfl_xor(d, dd, 64));
      const float s = __fadd_rn(__fadd_rn(__fmul_rn(-2.0f, d), zn), cbnorm[k]);
      const unsigned long long key = ((unsigned long long)f2mono(s) << 32) | (unsigned)k;
      best = (key < best) ? key : best;
    }
    if (lane == 0) atomicMin(&packed[q], best);
  }
}

// ---------------------------------------------------------------------------
// Exact fp32 rescore of (q,k) pairs (fallback path, R4-verified machinery).
// ---------------------------------------------------------------------------
__global__ __launch_bounds__(256) void exact_cand(const float* __restrict__ zT,
                                                  const float* __restrict__ cb,
                                                  const float* __restrict__ cbnorm,
                                                  const float* __restrict__ znorm,
                                                  const unsigned* __restrict__ pairs,
                                                  const int* __restrict__ paircount,
                                                  unsigned long long* __restrict__ packed) {
  const int cnt = min(*paircount, CAP_PAIRS);
  const int gw = (blockIdx.x * 256 + threadIdx.x) >> 6;
  const int nw = (gridDim.x * 256) >> 6;
  const int lane = threadIdx.x & 63;
  for (int p = gw; p < cnt; p += nw) {
    const unsigned qk = pairs[p];
    const int q = qk >> 13, k = qk & 8191;
    const float4 cv = ((const float4*)(cb + (size_t)k * FEAT))[lane];
    const float4 zv = ((const float4*)(zT + (size_t)q * FEAT))[lane];
    float d = __builtin_fmaf(zv.w, cv.w,
              __builtin_fmaf(zv.z, cv.z,
              __builtin_fmaf(zv.y, cv.y, __fmul_rn(zv.x, cv.x))));
#pragma unroll
    for (int dd = 1; dd < 64; dd <<= 1) d = __fadd_rn(d, __shfl_xor(d, dd, 64));
    const float s = __fadd_rn(__fadd_rn(__fmul_rn(-2.0f, d), znorm[q]), cbnorm[k]);
    if (lane == 0) {
      const unsigned long long key = ((unsigned long long)f2mono(s) << 32) | (unsigned)k;
      atomicMin(&packed[q], key);
    }
  }
}

// ---------------------------------------------------------------------------
// Gather: zq[b][c][hw] = cb[idx]; idx as float appended after zq.
// ---------------------------------------------------------------------------
__global__ __launch_bounds__(256) void vq_gather(const float* __restrict__ cb,
                                                 const unsigned long long* __restrict__ packed,
                                                 float* __restrict__ out) {
  const int q0 = blockIdx.x * 64;
  const int nl = threadIdx.x & 63;
  const int cg = threadIdx.x >> 6;
  const int q = q0 + nl;
  const int kq = (int)((unsigned)packed[q] & 8191u);
  const int b = q >> 10, hw = q & 1023;
  const float4* cb4 = (const float4*)cb;
#pragma unroll
  for (int t = 0; t < 16; ++t) {
    const int cc = cg + t * 4;
    const float4 v = cb4[kq * 64 + cc];
    const int base = b * (FEAT * 1024) + (cc * 4) * 1024 + hw;
    out[base] = v.x;
    out[base + 1024] = v.y;
    out[base + 2048] = v.z;
    out[base + 3072] = v.w;
  }
  if (threadIdx.x < 64) {
    const int qq = q0 + threadIdx.x;
    out[ZQ_ELEMS + qq] = (float)(int)((unsigned)packed[qq] & 8191u);
  }
}

extern "C" void kernel_launch(void* const* d_in, const int* in_sizes, int n_in,
                              void* d_out, int out_size, void* d_ws, size_t ws_size,
                              hipStream_t stream) {
  const float* z = (const float*)d_in[0];
  const float* cb = (const float*)d_in[1];
  char* w = (char*)d_ws;
  // ws layout: ~30 MiB fixed + 64 MiB group-min memo at MEMO_OFF
  char* At = w;                                            // 8 MB
  char* Bt = w + 8388608;                                  // 4 MB
  float* zT = (float*)(w + 12582912);                      // 16 MB
  float* cbnorm = (float*)(w + 29360128);                  // 32 KB
  float* znorm = (float*)(w + 29392896);                   // 64 KB
  unsigned* gmin = (unsigned*)(w + 29458432);              // 64 KB
  int* paircount = (int*)(w + 29523968);                   // 256 B
  unsigned* pairs = (unsigned*)(w + 29524224);             // 1 MB (256K entries)
  unsigned long long* packed = (unsigned long long*)(w + 30572800);  // 128 KB
  unsigned* memo = (unsigned*)(w + MEMO_OFF);              // 64 MiB fp16 group-mins

  const bool use_memo =
      ws_size >= (size_t)(MEMO_OFF + MEMO_BYTES);

  hipMemsetAsync(paircount, 0, 256, stream);
  hipMemsetAsync(gmin, 0xFF, NQ * sizeof(unsigned), stream);
  hipMemsetAsync(packed, 0xFF, NQ * sizeof(unsigned long long), stream);
  norms_kernel<<<(CODES + NQ) / 16, 256, 0, stream>>>(cb, z, cbnorm, znorm);
  convA<<<1024, 256, 0, stream>>>(z, At, zT);
  convB<<<512, 256, 0, stream>>>(cb, Bt);
  if (use_memo) {
    gemm_pass1m<<<(NQ / 128) * NSLICE, 256, 0, stream>>>(At, Bt, cbnorm, gmin, memo);
    scan_rm<<<2048, 256, 0, stream>>>(memo, gmin, pairs, paircount);
    exact4<<<512, 256, 0, stream>>>(zT, cb, cbnorm, znorm, pairs, paircount, packed);
  } else {
    gemm_pass1<<<(NQ / 128) * NSLICE, 256, 0, stream>>>(At, Bt, cbnorm, gmin);
    gemm_pass2<<<(NQ / 128) * NSLICE, 256, 0, stream>>>(At, Bt, cbnorm, gmin, pairs, paircount);
    exact_cand<<<512, 256, 0, stream>>>(zT, cb, cbnorm, znorm, pairs, paircount, packed);
  }
  vq_gather<<<NQ / 64, 256, 0, stream>>>(cb, packed, (float*)d_out);
}

// Round 10
// 191.067 us; speedup vs baseline: 4.0755x; 1.2087x over previous
//
#include <hip/hip_runtime.h>
#include <stdint.h>

#define FEAT 256
#define CODES 8192
#define NQ 16384                 // 16*32*32
#define ZQ_ELEMS (NQ * FEAT)
#define MARGIN 2e-3f             // = 2e bound on fp16 score error (R4-validated)
#define RM_ERR 1.0e-3f           // fp16 RNE storage err bound for |rm| < 2
#define NSLICE 8
#define CAP_PAIRS (1 << 18)      // 256K (fallback path only)
#define KSC (-0.0078125f)        // descale: acc * -2/256
#define MEMO_OFF 31457280ull     // 30 MiB: right after fixed ws region
#define MEMO_BYTES 67108864ull   // 64 MiB fp16 group-mins

typedef _Float16 f16x8 __attribute__((ext_vector_type(8)));
typedef float f32x4 __attribute__((ext_vector_type(4)));

__device__ __forceinline__ void async_lds16(void* lds, const void* g) {
  __builtin_amdgcn_global_load_lds(
      (const __attribute__((address_space(1))) void*)(uintptr_t)(g),
      (__attribute__((address_space(3))) void*)(uint32_t)(uintptr_t)(lds),
      16, 0, 0);
}

// monotone float<->uint order transform
__device__ __forceinline__ unsigned f2mono(float v) {
  unsigned u = __float_as_uint(v);
  return (u & 0x80000000u) ? ~u : (u | 0x80000000u);
}
__device__ __forceinline__ float mono2f(unsigned t) {
  unsigned u = (t & 0x80000000u) ? (t & 0x7fffffffu) : ~t;
  return __uint_as_float(u);
}
__device__ __forceinline__ unsigned pack_f16x2(float a, float b) {
  unsigned short ha = __builtin_bit_cast(unsigned short, (_Float16)a);
  unsigned short hb = __builtin_bit_cast(unsigned short, (_Float16)b);
  return (unsigned)ha | ((unsigned)hb << 16);
}

// ---------------------------------------------------------------------------
// numpy pairwise sum-of-squares replication (verified R1-R4, absmax 0).
// ---------------------------------------------------------------------------
template <int STRIDE>
__device__ __forceinline__ float pairwise256_sq(const float* __restrict__ base, int lane16) {
  const int h = lane16 >> 3, j = lane16 & 7;
  const float* p = base + (h * 128 + j) * STRIDE;
  float x = p[0];
  float r = __fmul_rn(x, x);
#pragma unroll
  for (int i = 1; i < 16; ++i) {
    float y = p[i * 8 * STRIDE];
    r = __fadd_rn(r, __fmul_rn(y, y));
  }
  r = __fadd_rn(r, __shfl_xor(r, 1, 64));
  r = __fadd_rn(r, __shfl_xor(r, 2, 64));
  r = __fadd_rn(r, __shfl_xor(r, 4, 64));
  float other = __shfl_xor(r, 8, 64);
  float lo = (h == 0) ? r : other;
  float hi = (h == 0) ? other : r;
  return __fadd_rn(lo, hi);
}

// ---------------------------------------------------------------------------
// prep: fused {norms | convA | convB | buffer-init} via block-range dispatch.
// Bodies are byte-identical to the R9-verified standalone kernels.
// blocks [0,1536): norms; [1536,2560): convA; [2560,3072): convB;
// [3072,3136): init gmin/packed/paircount.
// ---------------------------------------------------------------------------
#define PREP_BLOCKS 3136
__global__ __launch_bounds__(256) void prep(const float* __restrict__ cb,
                                            const float* __restrict__ z,
                                            float* __restrict__ cbnorm,
                                            float* __restrict__ znorm,
                                            char* __restrict__ At, float* __restrict__ zT,
                                            char* __restrict__ Bt,
                                            unsigned* __restrict__ gmin,
                                            unsigned long long* __restrict__ packed,
                                            int* __restrict__ paircount) {
  __shared__ __align__(16) char smem[128 * 40 * 2 + 128 * 36 * 4];
  const int bb0 = blockIdx.x;
  const int t = threadIdx.x;
  if (bb0 < 1536) {
    // ---- norms ----
    const int g = (bb0 * 256 + t) >> 4;
    const int lane16 = t & 15;
    if (g < CODES) {
      float v = pairwise256_sq<1>(cb + g * FEAT, lane16);
      if (lane16 == 0) cbnorm[g] = v;
    } else {
      const int q = g - CODES;
      const int b = q >> 10, hw = q & 1023;
      float v = pairwise256_sq<1024>(z + b * (FEAT * 1024) + hw, lane16);
      if (lane16 == 0) znorm[q] = v;
    }
  } else if (bb0 < 2560) {
    // ---- convA ----
    _Float16* T = (_Float16*)smem;
    float* Tf = (float*)(smem + 128 * 40 * 2);
    const int blk = bb0 - 1536;
    const int mt = blk >> 3, ct = blk & 7;
    const int q0 = mt * 128, bb = q0 >> 10, hw0 = q0 & 1023;
    const int c0 = ct * 32;
#pragma unroll
    for (int it = 0; it < 16; ++it) {
      const int cc = it * 2 + (t >> 7);
      const int qi = t & 127;
      float v = z[bb * (FEAT * 1024) + (c0 + cc) * 1024 + hw0 + qi];
      T[qi * 40 + cc] = (_Float16)v;
      Tf[qi * 36 + cc] = v;
    }
    __syncthreads();
    const int r = t >> 1, h = t & 1;
    {
      float4 a = *(const float4*)&T[r * 40 + h * 16];
      float4 b = *(const float4*)&T[r * 40 + h * 16 + 8];
      char* dst = At + (size_t)(mt * 8 + ct) * 8192 + t * 32;
      *(float4*)dst = a;
      *(float4*)(dst + 16) = b;
    }
    float* zrow = zT + (size_t)(q0 + r) * FEAT + c0 + h * 16;
#pragma unroll
    for (int e = 0; e < 4; ++e)
      *(float4*)(zrow + e * 4) = *(const float4*)&Tf[r * 36 + h * 16 + e * 4];
  } else if (bb0 < 3072) {
    // ---- convB (fragment-linear fp16, x256; verified R1-R9) ----
    const int T4 = (bb0 - 2560) * 256 + t;   // [0, 131072)
    const int K = T4 >> 4, part = T4 & 15;
    const float* src = cb + (size_t)K * FEAT + part * 16;
    const int nt = K >> 7, rem = K & 127;
    const int wn = rem >> 6, j = (rem >> 4) & 3, llo = rem & 15;
#pragma unroll
    for (int g = 0; g < 2; ++g) {
      const int c0 = part * 16 + g * 8;
      const int ct = c0 >> 5, lhi = (c0 >> 3) & 3;
      const int cg = nt * 8 + ct;
      f16x8 o;
#pragma unroll
      for (int e = 0; e < 8; ++e) o[e] = (_Float16)(src[g * 8 + e] * 256.0f);
      const size_t s = ((size_t)((cg * 2 + wn) * 4 + j) << 6) + (size_t)(lhi * 16 + llo);
      *(f16x8*)(Bt + s * 16) = o;
    }
  } else {
    // ---- init ----
    const int bi = bb0 - 3072;
    const int idx = bi * 256 + t;   // [0, 16384)
    gmin[idx] = 0xFFFFFFFFu;
    packed[idx] = ~0ull;
    if (bi == 0 && t < 64) paircount[t] = 0;
  }
}

// ---------------------------------------------------------------------------
// Shared GEMM body, R2-proven structure: A-tile (64 KB, all K) resident in
// LDS; B chunks (8 KB) double-buffered via global_load_lds, counted vmcnt(2)
// waits, raw s_barriers, sched_barrier(0) fences.
// PASS=0: per-row running min -> atomicMin gmin[q].
// PASS=1: (fallback pass2) push (q<<13|k) for score <= gmin[q]+MARGIN.
// PASS=3: PASS0 + store per-(row,tile) 4-k group-min rm_ as packed fp16x2.
//         memo layout (uints): ((((blk*8+nt)*4+wave)*8)+rp)*64 + lane,
//         uint = f16x2(rm[2rp], rm[2rp+1]). 64 MiB total. (R9-verified)
// ---------------------------------------------------------------------------
template <int PASS>
__device__ __forceinline__ void gemm_body(const char* __restrict__ At,
                                          const char* __restrict__ Bt,
                                          const float* __restrict__ cbnorm,
                                          unsigned* __restrict__ gmin,
                                          unsigned* __restrict__ pairs,
                                          int* __restrict__ paircount,
                                          unsigned* __restrict__ memo) {
  __shared__ __align__(16) char Af[65536];
  __shared__ __align__(16) char Bs0[8192];
  __shared__ __align__(16) char Bs1[8192];

  const int tid = threadIdx.x;
  const int slice = blockIdx.x & 7, mt = blockIdx.x >> 3;
  const int wave = tid >> 6, lane = tid & 63;
  const int wm = wave >> 1, wn = wave & 1;
  const int col = lane & 15, quad = lane >> 4;

  const int srow = wave * 32 + (lane >> 2);  // A staging row within 32-row group
  const int ss = lane & 3;
  const char* Abase = At + (size_t)(mt * 8) * 8192;
  const char* Bslice = Bt + (size_t)slice * 524288;

  // stage entire A tile (8 ct-chunks) into LDS, swizzled slots
#pragma unroll
  for (int ct = 0; ct < 8; ++ct) {
#pragma unroll
    for (int i = 0; i < 2; ++i) {
      const int r = srow + i * 16;
      const int cs = ss ^ ((r >> 1) & 3);
      async_lds16(Af + ct * 8192 + wave * 2048 + i * 1024,
                  Abase + (size_t)ct * 8192 + r * 64 + cs * 16);
    }
  }

#define STAGE_B(BUF, CIDX)                                                          \
  do {                                                                              \
    const char* gs_ = Bslice + ((size_t)(CIDX) << 13) + wave * 2048 + lane * 16;    \
    async_lds16((BUF) + wave * 2048, gs_);                                          \
    async_lds16((BUF) + wave * 2048 + 1024, gs_ + 1024);                            \
  } while (0)

  // prime double-buffer: chunks 0 and 1
  STAGE_B(Bs0, 0);
  STAGE_B(Bs1, 1);

  int aoff[4];
#pragma unroll
  for (int i = 0; i < 4; ++i) {
    const int m = wm * 64 + i * 16 + col;
    aoff[i] = m * 64 + ((quad ^ ((m >> 1) & 3)) << 4);
  }

  int qrow[16];
#pragma unroll
  for (int row = 0; row < 16; ++row)
    qrow[row] = mt * 128 + wm * 64 + (row >> 2) * 16 + quad * 4 + (row & 3);

  float vmin[16], thr[16];
#pragma unroll
  for (int row = 0; row < 16; ++row) vmin[row] = 3.4e38f;
  if (PASS == 1) {
#pragma unroll
    for (int row = 0; row < 16; ++row) thr[row] = mono2f(gmin[qrow[row]]) + MARGIN;
  }

  f32x4 acc[4][4];

  __syncthreads();  // full drain once: A tile + B chunks 0,1 landed

#define CHUNK(CT, STG, CNEXT, WMODE)                                                \
  do {                                                                              \
    char* Bcur_ = ((CT) & 1) ? Bs1 : Bs0;                                           \
    f16x8 bf_[4], af_[4];                                                           \
    _Pragma("unroll") for (int j = 0; j < 4; ++j)                                   \
        bf_[j] = *(const f16x8*)(Bcur_ + wn * 4096 + j * 1024 + lane * 16);         \
    _Pragma("unroll") for (int i = 0; i < 4; ++i)                                   \
        af_[i] = *(const f16x8*)(Af + (CT) * 8192 + aoff[i]);                       \
    asm volatile("s_waitcnt lgkmcnt(0)" ::: "memory");                              \
    __builtin_amdgcn_sched_barrier(0);                                              \
    __builtin_amdgcn_s_barrier(); /* all waves done reading Bcur_ */                \
    if (STG) {                                                                      \
      STAGE_B(Bcur_, CNEXT);                                                        \
      __builtin_amdgcn_sched_barrier(0); /* keep loads issued before MFMA */        \
    }                                                                               \
    _Pragma("unroll") for (int i = 0; i < 4; ++i)                                   \
        _Pragma("unroll") for (int j = 0; j < 4; ++j)                               \
            acc[i][j] = __builtin_amdgcn_mfma_f32_16x16x32_f16(af_[i], bf_[j],      \
                                                               acc[i][j], 0, 0, 0); \
    if ((WMODE) == 2) {                                                             \
      asm volatile("s_waitcnt vmcnt(2)" ::: "memory");                              \
      __builtin_amdgcn_sched_barrier(0);                                            \
    }                                                                               \
    if ((WMODE) == 0) {                                                             \
      asm volatile("s_waitcnt vmcnt(0)" ::: "memory");                              \
      __builtin_amdgcn_sched_barrier(0);                                            \
    }                                                                               \
    __builtin_amdgcn_s_barrier(); /* next buffer staged for all waves */            \
  } while (0)

#define ZEROACC                                                                     \
  do {                                                                              \
    _Pragma("unroll") for (int i = 0; i < 4; ++i)                                   \
        _Pragma("unroll") for (int j = 0; j < 4; ++j)                               \
            acc[i][j] = (f32x4){0.f, 0.f, 0.f, 0.f};                                \
  } while (0)

#define SCORING(NT)                                                                 \
  do {                                                                              \
    const int k0_ = (slice * 8 + (NT)) * 128;                                       \
    float cn_[4];                                                                   \
    _Pragma("unroll") for (int j = 0; j < 4; ++j)                                   \
        cn_[j] = cbnorm[k0_ + wn * 64 + j * 16 + col];                              \
    unsigned* sb_ = (PASS == 3)                                                     \
        ? memo + ((((unsigned)blockIdx.x * 8u + (unsigned)(NT)) * 4u +              \
                   (unsigned)wave) * 8u) * 64u + (unsigned)lane                     \
        : nullptr;                                                                  \
    float prev_ = 0.f;                                                              \
    _Pragma("unroll") for (int i = 0; i < 4; ++i)                                   \
        _Pragma("unroll") for (int r = 0; r < 4; ++r) {                             \
      const int row_ = i * 4 + r;                                                   \
      const float s0_ = __builtin_fmaf(acc[i][0][r], KSC, cn_[0]);                  \
      const float s1_ = __builtin_fmaf(acc[i][1][r], KSC, cn_[1]);                  \
      const float s2_ = __builtin_fmaf(acc[i][2][r], KSC, cn_[2]);                  \
      const float s3_ = __builtin_fmaf(acc[i][3][r], KSC, cn_[3]);                  \
      const float rm_ = fminf(fminf(s0_, s1_), fminf(s2_, s3_));                    \
      if (PASS != 1) {                                                              \
        vmin[row_] = fminf(vmin[row_], rm_);                                        \
        if (PASS == 3) {                                                            \
          if ((r & 1) == 0) prev_ = rm_;                                            \
          else sb_[(unsigned)((i * 2 + (r >> 1)) * 64)] = pack_f16x2(prev_, rm_);   \
        }                                                                           \
      } else if (rm_ <= thr[row_]) { /* exact early-out: min_j > thr => none */     \
        const float sv_[4] = {s0_, s1_, s2_, s3_};                                  \
        _Pragma("unroll") for (int j = 0; j < 4; ++j) {                             \
          if (sv_[j] <= thr[row_]) {                                                \
            const int slot_ = atomicAdd(paircount, 1);                              \
            if (slot_ < CAP_PAIRS)                                                  \
              pairs[slot_] = ((unsigned)qrow[row_] << 13) |                         \
                             (unsigned)(k0_ + wn * 64 + j * 16 + col);              \
          }                                                                         \
        }                                                                           \
      }                                                                             \
    }                                                                               \
  } while (0)

  for (int nt = 0; nt < 7; ++nt) {
    ZEROACC;
#pragma unroll
    for (int ct = 0; ct < 8; ++ct) CHUNK(ct, true, nt * 8 + ct + 2, 2);
    SCORING(nt);
  }
  // nt = 7 epilogue: stop staging at chunk 63, then drain
  ZEROACC;
  CHUNK(0, true, 58, 2);
  CHUNK(1, true, 59, 2);
  CHUNK(2, true, 60, 2);
  CHUNK(3, true, 61, 2);
  CHUNK(4, true, 62, 2);
  CHUNK(5, true, 63, 2);
  CHUNK(6, false, 0, 0);
  CHUNK(7, false, 0, 3);
  SCORING(7);

#undef STAGE_B
#undef CHUNK
#undef ZEROACC
#undef SCORING

  if (PASS != 1) {
    // cross-col min (value only), then atomicMin per row
#pragma unroll
    for (int row = 0; row < 16; ++row) {
      float v = vmin[row];
      v = fminf(v, __shfl_xor(v, 1, 64));
      v = fminf(v, __shfl_xor(v, 2, 64));
      v = fminf(v, __shfl_xor(v, 4, 64));
      v = fminf(v, __shfl_xor(v, 8, 64));
      if (col == 0) atomicMin(&gmin[qrow[row]], f2mono(v));
    }
  }
}

__global__ __launch_bounds__(256, 2) void gemm_pass1(const char* __restrict__ At,
                                                     const char* __restrict__ Bt,
                                                     const float* __restrict__ cbnorm,
                                                     unsigned* __restrict__ gmin) {
  gemm_body<0>(At, Bt, cbnorm, gmin, nullptr, nullptr, nullptr);
}

__global__ __launch_bounds__(256, 2) void gemm_pass1m(const char* __restrict__ At,
                                                      const char* __restrict__ Bt,
                                                      const float* __restrict__ cbnorm,
                                                      unsigned* __restrict__ gmin,
                                                      unsigned* __restrict__ memo) {
  gemm_body<3>(At, Bt, cbnorm, gmin, nullptr, nullptr, memo);
}

__global__ __launch_bounds__(256, 2) void gemm_pass2(const char* __restrict__ At,
                                                     const char* __restrict__ Bt,
                                                     const float* __restrict__ cbnorm,
                                                     unsigned* __restrict__ gmin,
                                                     unsigned* __restrict__ pairs,
                                                     int* __restrict__ paircount) {
  gemm_body<1>(At, Bt, cbnorm, gmin, pairs, paircount, nullptr);
}

// ---------------------------------------------------------------------------
// scan_exact: stream the 64 MiB fp16 group-min memo (decode identical to the
// R9-verified scan_rm); for each hit (stored rm <= gmin[q]+MARGIN+RM_ERR),
// the WHOLE WAVE immediately rescores the 4-k group with the R4-verified
// exact fp32 chain and atomicMin's the per-q winner. Per-lane hit BITMASK
// (no arrays -> no scratch); wave-coop loop via ballot/ffs/shfl. No pairs
// buffer, no hot atomic, one kernel instead of two.
// id encoding: (q << 11) | (ntile << 5) | (wn << 4) | col.
// ---------------------------------------------------------------------------
__global__ __launch_bounds__(256) void scan_exact(const unsigned* __restrict__ memo,
                                                  const unsigned* __restrict__ gmin,
                                                  const float* __restrict__ zT,
                                                  const float* __restrict__ cb,
                                                  const float* __restrict__ cbnorm,
                                                  const float* __restrict__ znorm,
                                                  unsigned long long* __restrict__ packed) {
  const unsigned NU4 = 4194304u;  // 64 MiB / 16
  const unsigned stride = gridDim.x * blockDim.x;  // 524288 divides NU4: uniform trip count
  const int lane = threadIdx.x & 63;
  for (unsigned U = blockIdx.x * 256 + threadIdx.x; U < NU4; U += stride) {
    const uint4 v = ((const uint4*)memo)[U];
    const unsigned u = U << 2;
    const unsigned lane0 = u & 63, col0 = lane0 & 15, quad = lane0 >> 4;
    const unsigned rp = (u >> 6) & 7;
    const unsigned w = (u >> 9) & 3;
    const unsigned t = (u >> 11) & 7;
    const unsigned blk = u >> 14;
    const unsigned mt = blk >> 3, slice = blk & 7;
    const unsigned wm = w >> 1, wn = w & 1;
    const unsigned ntile = slice * 8u + t;
    const unsigned row0 = rp * 2u;
    const int q0 = (int)(mt * 128u + wm * 64u + (row0 >> 2) * 16u + quad * 4u + (row0 & 3u));
    const float thr0 = mono2f(gmin[q0]) + (MARGIN + RM_ERR);
    const float thr1 = mono2f(gmin[q0 + 1]) + (MARGIN + RM_ERR);
    const unsigned wv[4] = {v.x, v.y, v.z, v.w};
    unsigned hm = 0;  // bit = wi*2 + h  (h=0 -> q0, h=1 -> q0+1)
#pragma unroll
    for (int wi = 0; wi < 4; ++wi) {
      const float lo = (float)__builtin_bit_cast(_Float16, (unsigned short)(wv[wi] & 0xffffu));
      const float hi = (float)__builtin_bit_cast(_Float16, (unsigned short)(wv[wi] >> 16));
      if (lo <= thr0) hm |= 1u << (wi * 2);
      if (hi <= thr1) hm |= 1u << (wi * 2 + 1);
    }
    // wave-cooperative rescore of each hit (rare: ~19K hits / 33.5M groups)
    while (true) {
      const unsigned long long act = __ballot(hm != 0);
      if (!act) break;
      const int src = (int)(__ffsll((unsigned long long)act) - 1);
      // per-lane id of its lowest-set hit (only src's value is used)
      unsigned myid = 0;
      {
        const int bit = __ffs((int)hm) - 1;
        if (bit >= 0) {
          const unsigned wi = (unsigned)bit >> 1, h = (unsigned)bit & 1;
          const unsigned kid = (ntile << 5) | (wn << 4) | (col0 + wi);
          myid = ((unsigned)(q0 + (int)h) << 11) | kid;
        }
      }
      const unsigned id = (unsigned)__shfl((int)myid, src, 64);
      // full-wave exact fp32 rescore of group id (R4-verified chain)
      const int q = (int)(id >> 11);
      const int base = (int)(((id >> 5) & 63u) * 128u + ((id >> 4) & 1u) * 64u + (id & 15u));
      const float4 zv = ((const float4*)(zT + (size_t)q * FEAT))[lane];
      const float zn = znorm[q];
      unsigned long long best = ~0ull;
#pragma unroll
      for (int j = 0; j < 4; ++j) {
        const int k = base + j * 16;
        const float4 cv = ((const float4*)(cb + (size_t)k * FEAT))[lane];
        float d = __builtin_fmaf(zv.w, cv.w,
                  __builtin_fmaf(zv.z, cv.z,
                  __builtin_fmaf(zv.y, cv.y, __fmul_rn(zv.x, cv.x))));
#pragma unroll
        for (int dd = 1; dd < 64; dd <<= 1) d = __fadd_rn(d, __shfl_xor(d, dd, 64));
        const float s = __fadd_rn(__fadd_rn(__fmul_rn(-2.0f, d), zn), cbnorm[k]);
        const unsigned long long key = ((unsigned long long)f2mono(s) << 32) | (unsigned)k;
        best = (key < best) ? key : best;
      }
      if (lane == 0) atomicMin(&packed[q], best);
      if (lane == src) hm &= hm - 1;  // clear processed hit
    }
  }
}

// ---------------------------------------------------------------------------
// Exact fp32 rescore of (q,k) pairs (fallback path, R4-verified machinery).
// ---------------------------------------------------------------------------
__global__ __launch_bounds__(256) void exact_cand(const float* __restrict__ zT,
                                                  const float* __restrict__ cb,
                                                  const float* __restrict__ cbnorm,
                                                  const float* __restrict__ znorm,
                                                  const unsigned* __restrict__ pairs,
                                                  const int* __restrict__ paircount,
                                                  unsigned long long* __restrict__ packed) {
  const int cnt = min(*paircount, CAP_PAIRS);
  const int gw = (blockIdx.x * 256 + threadIdx.x) >> 6;
  const int nw = (gridDim.x * 256) >> 6;
  const int lane = threadIdx.x & 63;
  for (int p = gw; p < cnt; p += nw) {
    const unsigned qk = pairs[p];
    const int q = qk >> 13, k = qk & 8191;
    const float4 cv = ((const float4*)(cb + (size_t)k * FEAT))[lane];
    const float4 zv = ((const float4*)(zT + (size_t)q * FEAT))[lane];
    float d = __builtin_fmaf(zv.w, cv.w,
              __builtin_fmaf(zv.z, cv.z,
              __builtin_fmaf(zv.y, cv.y, __fmul_rn(zv.x, cv.x))));
#pragma unroll
    for (int dd = 1; dd < 64; dd <<= 1) d = __fadd_rn(d, __shfl_xor(d, dd, 64));
    const float s = __fadd_rn(__fadd_rn(__fmul_rn(-2.0f, d), znorm[q]), cbnorm[k]);
    if (lane == 0) {
      const unsigned long long key = ((unsigned long long)f2mono(s) << 32) | (unsigned)k;
      atomicMin(&packed[q], key);
    }
  }
}

// ---------------------------------------------------------------------------
// Gather: zq[b][c][hw] = cb[idx]; idx as float appended after zq.
// ---------------------------------------------------------------------------
__global__ __launch_bounds__(256) void vq_gather(const float* __restrict__ cb,
                                                 const unsigned long long* __restrict__ packed,
                                                 float* __restrict__ out) {
  const int q0 = blockIdx.x * 64;
  const int nl = threadIdx.x & 63;
  const int cg = threadIdx.x >> 6;
  const int q = q0 + nl;
  const int kq = (int)((unsigned)packed[q] & 8191u);
  const int b = q >> 10, hw = q & 1023;
  const float4* cb4 = (const float4*)cb;
#pragma unroll
  for (int t = 0; t < 16; ++t) {
    const int cc = cg + t * 4;
    const float4 v = cb4[kq * 64 + cc];
    const int base = b * (FEAT * 1024) + (cc * 4) * 1024 + hw;
    out[base] = v.x;
    out[base + 1024] = v.y;
    out[base + 2048] = v.z;
    out[base + 3072] = v.w;
  }
  if (threadIdx.x < 64) {
    const int qq = q0 + threadIdx.x;
    out[ZQ_ELEMS + qq] = (float)(int)((unsigned)packed[qq] & 8191u);
  }
}

extern "C" void kernel_launch(void* const* d_in, const int* in_sizes, int n_in,
                              void* d_out, int out_size, void* d_ws, size_t ws_size,
                              hipStream_t stream) {
  const float* z = (const float*)d_in[0];
  const float* cb = (const float*)d_in[1];
  char* w = (char*)d_ws;
  // ws layout: ~30 MiB fixed + 64 MiB group-min memo at MEMO_OFF
  char* At = w;                                            // 8 MB
  char* Bt = w + 8388608;                                  // 4 MB
  float* zT = (float*)(w + 12582912);                      // 16 MB
  float* cbnorm = (float*)(w + 29360128);                  // 32 KB
  float* znorm = (float*)(w + 29392896);                   // 64 KB
  unsigned* gmin = (unsigned*)(w + 29458432);              // 64 KB
  int* paircount = (int*)(w + 29523968);                   // 256 B
  unsigned* pairs = (unsigned*)(w + 29524224);             // 1 MB (fallback only)
  unsigned long long* packed = (unsigned long long*)(w + 30572800);  // 128 KB
  unsigned* memo = (unsigned*)(w + MEMO_OFF);              // 64 MiB fp16 group-mins

  const bool use_memo = ws_size >= (size_t)(MEMO_OFF + MEMO_BYTES);

  prep<<<PREP_BLOCKS, 256, 0, stream>>>(cb, z, cbnorm, znorm, At, zT, Bt,
                                        gmin, packed, paircount);
  if (use_memo) {
    gemm_pass1m<<<(NQ / 128) * NSLICE, 256, 0, stream>>>(At, Bt, cbnorm, gmin, memo);
    scan_exact<<<2048, 256, 0, stream>>>(memo, gmin, zT, cb, cbnorm, znorm, packed);
  } else {
    gemm_pass1<<<(NQ / 128) * NSLICE, 256, 0, stream>>>(At, Bt, cbnorm, gmin);
    gemm_pass2<<<(NQ / 128) * NSLICE, 256, 0, stream>>>(At, Bt, cbnorm, gmin, pairs, paircount);
    exact_cand<<<512, 256, 0, stream>>>(zT, cb, cbnorm, znorm, pairs, paircount, packed);
  }
  vq_gather<<<NQ / 64, 256, 0, stream>>>(cb, packed, (float*)d_out);
}

// Round 11
// 187.404 us; speedup vs baseline: 4.1551x; 1.0195x over previous
//
#include <hip/hip_runtime.h>
#include <stdint.h>

#define FEAT 256
#define CODES 8192
#define NQ 16384                 // 16*32*32
#define ZQ_ELEMS (NQ * FEAT)
#define MARGIN 2e-3f             // = 2e bound on fp16 score error (R4-validated)
#define RM_ERR 1.0e-3f           // fp16 RNE storage err bound for |rm| < 2
#define NSLICE 8
#define CAP_PAIRS (1 << 18)      // 256K (fallback path only)
#define KSC (-0.0078125f)        // descale: acc * -2/256
#define MEMO_OFF 31457280ull     // 30 MiB: right after fixed ws region
#define MEMO_BYTES 67108864ull   // 64 MiB fp16 group-mins

typedef _Float16 f16x8 __attribute__((ext_vector_type(8)));
typedef float f32x4 __attribute__((ext_vector_type(4)));

__device__ __forceinline__ void async_lds16(void* lds, const void* g) {
  __builtin_amdgcn_global_load_lds(
      (const __attribute__((address_space(1))) void*)(uintptr_t)(g),
      (__attribute__((address_space(3))) void*)(uint32_t)(uintptr_t)(lds),
      16, 0, 0);
}

// monotone float<->uint order transform
__device__ __forceinline__ unsigned f2mono(float v) {
  unsigned u = __float_as_uint(v);
  return (u & 0x80000000u) ? ~u : (u | 0x80000000u);
}
__device__ __forceinline__ float mono2f(unsigned t) {
  unsigned u = (t & 0x80000000u) ? (t & 0x7fffffffu) : ~t;
  return __uint_as_float(u);
}
__device__ __forceinline__ unsigned pack_f16x2(float a, float b) {
  unsigned short ha = __builtin_bit_cast(unsigned short, (_Float16)a);
  unsigned short hb = __builtin_bit_cast(unsigned short, (_Float16)b);
  return (unsigned)ha | ((unsigned)hb << 16);
}

// ---------------------------------------------------------------------------
// numpy pairwise sum-of-squares replication (verified R1-R4, absmax 0).
// Visits element indices (h*128 + j + 8i) in identical order for any STRIDE,
// so <1> on a transposed contiguous copy is bit-identical to <1024> on z.
// ---------------------------------------------------------------------------
template <int STRIDE>
__device__ __forceinline__ float pairwise256_sq(const float* __restrict__ base, int lane16) {
  const int h = lane16 >> 3, j = lane16 & 7;
  const float* p = base + (h * 128 + j) * STRIDE;
  float x = p[0];
  float r = __fmul_rn(x, x);
#pragma unroll
  for (int i = 1; i < 16; ++i) {
    float y = p[i * 8 * STRIDE];
    r = __fadd_rn(r, __fmul_rn(y, y));
  }
  r = __fadd_rn(r, __shfl_xor(r, 1, 64));
  r = __fadd_rn(r, __shfl_xor(r, 2, 64));
  r = __fadd_rn(r, __shfl_xor(r, 4, 64));
  float other = __shfl_xor(r, 8, 64);
  float lo = (h == 0) ? r : other;
  float hi = (h == 0) ? other : r;
  return __fadd_rn(lo, hi);
}

// ---------------------------------------------------------------------------
// prep: fused {cbnorm | convA | convB | buffer-init} via block-range dispatch.
// Bodies byte-identical to the R9/R10-verified kernels. znorm moved OUT
// (now computed from zT, coalesced, in znorm_zt).
// blocks [0,512): cbnorm; [512,1536): convA; [1536,2048): convB;
// [2048,2112): init gmin/packed/paircount.
// ---------------------------------------------------------------------------
#define PREP_BLOCKS 2112
__global__ __launch_bounds__(256) void prep(const float* __restrict__ cb,
                                            const float* __restrict__ z,
                                            float* __restrict__ cbnorm,
                                            char* __restrict__ At, float* __restrict__ zT,
                                            char* __restrict__ Bt,
                                            unsigned* __restrict__ gmin,
                                            unsigned long long* __restrict__ packed,
                                            int* __restrict__ paircount) {
  __shared__ __align__(16) char smem[128 * 40 * 2 + 128 * 36 * 4];
  const int bb0 = blockIdx.x;
  const int t = threadIdx.x;
  if (bb0 < 512) {
    // ---- cbnorm ----
    const int g = (bb0 * 256 + t) >> 4;   // [0, 8192)
    const int lane16 = t & 15;
    float v = pairwise256_sq<1>(cb + g * FEAT, lane16);
    if (lane16 == 0) cbnorm[g] = v;
  } else if (bb0 < 1536) {
    // ---- convA ----
    _Float16* T = (_Float16*)smem;
    float* Tf = (float*)(smem + 128 * 40 * 2);
    const int blk = bb0 - 512;
    const int mt = blk >> 3, ct = blk & 7;
    const int q0 = mt * 128, bb = q0 >> 10, hw0 = q0 & 1023;
    const int c0 = ct * 32;
#pragma unroll
    for (int it = 0; it < 16; ++it) {
      const int cc = it * 2 + (t >> 7);
      const int qi = t & 127;
      float v = z[bb * (FEAT * 1024) + (c0 + cc) * 1024 + hw0 + qi];
      T[qi * 40 + cc] = (_Float16)v;
      Tf[qi * 36 + cc] = v;
    }
    __syncthreads();
    const int r = t >> 1, h = t & 1;
    {
      float4 a = *(const float4*)&T[r * 40 + h * 16];
      float4 b = *(const float4*)&T[r * 40 + h * 16 + 8];
      char* dst = At + (size_t)(mt * 8 + ct) * 8192 + t * 32;
      *(float4*)dst = a;
      *(float4*)(dst + 16) = b;
    }
    float* zrow = zT + (size_t)(q0 + r) * FEAT + c0 + h * 16;
#pragma unroll
    for (int e = 0; e < 4; ++e)
      *(float4*)(zrow + e * 4) = *(const float4*)&Tf[r * 36 + h * 16 + e * 4];
  } else if (bb0 < 2048) {
    // ---- convB (fragment-linear fp16, x256; verified R1-R10) ----
    const int T4 = (bb0 - 1536) * 256 + t;   // [0, 131072)
    const int K = T4 >> 4, part = T4 & 15;
    const float* src = cb + (size_t)K * FEAT + part * 16;
    const int nt = K >> 7, rem = K & 127;
    const int wn = rem >> 6, j = (rem >> 4) & 3, llo = rem & 15;
#pragma unroll
    for (int g = 0; g < 2; ++g) {
      const int c0 = part * 16 + g * 8;
      const int ct = c0 >> 5, lhi = (c0 >> 3) & 3;
      const int cg = nt * 8 + ct;
      f16x8 o;
#pragma unroll
      for (int e = 0; e < 8; ++e) o[e] = (_Float16)(src[g * 8 + e] * 256.0f);
      const size_t s = ((size_t)((cg * 2 + wn) * 4 + j) << 6) + (size_t)(lhi * 16 + llo);
      *(f16x8*)(Bt + s * 16) = o;
    }
  } else {
    // ---- init ----
    const int bi = bb0 - 2048;
    const int idx = bi * 256 + t;   // [0, 16384)
    gmin[idx] = 0xFFFFFFFFu;
    packed[idx] = ~0ull;
    if (bi == 0 && t < 64) paircount[t] = 0;
  }
}

// ---------------------------------------------------------------------------
// znorm_zt: znorm[q] from the contiguous transposed copy zT (exact fp32 copy
// of z, written by convA). pairwise256_sq<1> executes bit-identical ops in
// bit-identical order as the old pairwise256_sq<1024> on z -> absmax 0.
// Coalesced 16 MB L2-warm read replaces the old 64 MB stride-4KB read.
// ---------------------------------------------------------------------------
__global__ __launch_bounds__(256) void znorm_zt(const float* __restrict__ zT,
                                                float* __restrict__ znorm) {
  const int q = (blockIdx.x * 256 + threadIdx.x) >> 4;   // [0, 16384)
  const int lane16 = threadIdx.x & 15;
  float v = pairwise256_sq<1>(zT + (size_t)q * FEAT, lane16);
  if (lane16 == 0) znorm[q] = v;
}

// ---------------------------------------------------------------------------
// Shared GEMM body, R2-proven structure: A-tile (64 KB, all K) resident in
// LDS; B chunks (8 KB) double-buffered via global_load_lds, counted vmcnt(2)
// waits, raw s_barriers, sched_barrier(0) fences.
// PASS=0: per-row running min -> atomicMin gmin[q].
// PASS=1: (fallback pass2) push (q<<13|k) for score <= gmin[q]+MARGIN.
// PASS=3: PASS0 + store per-(row,tile) 4-k group-min rm_ as packed fp16x2.
//         memo layout (uints): ((((blk*8+nt)*4+wave)*8)+rp)*64 + lane,
//         uint = f16x2(rm[2rp], rm[2rp+1]). 64 MiB total. (R9/R10-verified)
// ---------------------------------------------------------------------------
template <int PASS>
__device__ __forceinline__ void gemm_body(const char* __restrict__ At,
                                          const char* __restrict__ Bt,
                                          const float* __restrict__ cbnorm,
                                          unsigned* __restrict__ gmin,
                                          unsigned* __restrict__ pairs,
                                          int* __restrict__ paircount,
                                          unsigned* __restrict__ memo) {
  __shared__ __align__(16) char Af[65536];
  __shared__ __align__(16) char Bs0[8192];
  __shared__ __align__(16) char Bs1[8192];

  const int tid = threadIdx.x;
  const int slice = blockIdx.x & 7, mt = blockIdx.x >> 3;
  const int wave = tid >> 6, lane = tid & 63;
  const int wm = wave >> 1, wn = wave & 1;
  const int col = lane & 15, quad = lane >> 4;

  const int srow = wave * 32 + (lane >> 2);  // A staging row within 32-row group
  const int ss = lane & 3;
  const char* Abase = At + (size_t)(mt * 8) * 8192;
  const char* Bslice = Bt + (size_t)slice * 524288;

  // stage entire A tile (8 ct-chunks) into LDS, swizzled slots
#pragma unroll
  for (int ct = 0; ct < 8; ++ct) {
#pragma unroll
    for (int i = 0; i < 2; ++i) {
      const int r = srow + i * 16;
      const int cs = ss ^ ((r >> 1) & 3);
      async_lds16(Af + ct * 8192 + wave * 2048 + i * 1024,
                  Abase + (size_t)ct * 8192 + r * 64 + cs * 16);
    }
  }

#define STAGE_B(BUF, CIDX)                                                          \
  do {                                                                              \
    const char* gs_ = Bslice + ((size_t)(CIDX) << 13) + wave * 2048 + lane * 16;    \
    async_lds16((BUF) + wave * 2048, gs_);                                          \
    async_lds16((BUF) + wave * 2048 + 1024, gs_ + 1024);                            \
  } while (0)

  // prime double-buffer: chunks 0 and 1
  STAGE_B(Bs0, 0);
  STAGE_B(Bs1, 1);

  int aoff[4];
#pragma unroll
  for (int i = 0; i < 4; ++i) {
    const int m = wm * 64 + i * 16 + col;
    aoff[i] = m * 64 + ((quad ^ ((m >> 1) & 3)) << 4);
  }

  int qrow[16];
#pragma unroll
  for (int row = 0; row < 16; ++row)
    qrow[row] = mt * 128 + wm * 64 + (row >> 2) * 16 + quad * 4 + (row & 3);

  float vmin[16], thr[16];
#pragma unroll
  for (int row = 0; row < 16; ++row) vmin[row] = 3.4e38f;
  if (PASS == 1) {
#pragma unroll
    for (int row = 0; row < 16; ++row) thr[row] = mono2f(gmin[qrow[row]]) + MARGIN;
  }

  f32x4 acc[4][4];

  __syncthreads();  // full drain once: A tile + B chunks 0,1 landed

#define CHUNK(CT, STG, CNEXT, WMODE)                                                \
  do {                                                                              \
    char* Bcur_ = ((CT) & 1) ? Bs1 : Bs0;                                           \
    f16x8 bf_[4], af_[4];                                                           \
    _Pragma("unroll") for (int j = 0; j < 4; ++j)                                   \
        bf_[j] = *(const f16x8*)(Bcur_ + wn * 4096 + j * 1024 + lane * 16);         \
    _Pragma("unroll") for (int i = 0; i < 4; ++i)                                   \
        af_[i] = *(const f16x8*)(Af + (CT) * 8192 + aoff[i]);                       \
    asm volatile("s_waitcnt lgkmcnt(0)" ::: "memory");                              \
    __builtin_amdgcn_sched_barrier(0);                                              \
    __builtin_amdgcn_s_barrier(); /* all waves done reading Bcur_ */                \
    if (STG) {                                                                      \
      STAGE_B(Bcur_, CNEXT);                                                        \
      __builtin_amdgcn_sched_barrier(0); /* keep loads issued before MFMA */        \
    }                                                                               \
    _Pragma("unroll") for (int i = 0; i < 4; ++i)                                   \
        _Pragma("unroll") for (int j = 0; j < 4; ++j)                               \
            acc[i][j] = __builtin_amdgcn_mfma_f32_16x16x32_f16(af_[i], bf_[j],      \
                                                               acc[i][j], 0, 0, 0); \
    if ((WMODE) == 2) {                                                             \
      asm volatile("s_waitcnt vmcnt(2)" ::: "memory");                              \
      __builtin_amdgcn_sched_barrier(0);                                            \
    }                                                                               \
    if ((WMODE) == 0) {                                                             \
      asm volatile("s_waitcnt vmcnt(0)" ::: "memory");                              \
      __builtin_amdgcn_sched_barrier(0);                                            \
    }                                                                               \
    __builtin_amdgcn_s_barrier(); /* next buffer staged for all waves */            \
  } while (0)

#define ZEROACC                                                                     \
  do {                                                                              \
    _Pragma("unroll") for (int i = 0; i < 4; ++i)                                   \
        _Pragma("unroll") for (int j = 0; j < 4; ++j)                               \
            acc[i][j] = (f32x4){0.f, 0.f, 0.f, 0.f};                                \
  } while (0)

#define SCORING(NT)                                                                 \
  do {                                                                              \
    const int k0_ = (slice * 8 + (NT)) * 128;                                       \
    float cn_[4];                                                                   \
    _Pragma("unroll") for (int j = 0; j < 4; ++j)                                   \
        cn_[j] = cbnorm[k0_ + wn * 64 + j * 16 + col];                              \
    unsigned* sb_ = (PASS == 3)                                                     \
        ? memo + ((((unsigned)blockIdx.x * 8u + (unsigned)(NT)) * 4u +              \
                   (unsigned)wave) * 8u) * 64u + (unsigned)lane                     \
        : nullptr;                                                                  \
    float prev_ = 0.f;                                                              \
    _Pragma("unroll") for (int i = 0; i < 4; ++i)                                   \
        _Pragma("unroll") for (int r = 0; r < 4; ++r) {                             \
      const int row_ = i * 4 + r;                                                   \
      const float s0_ = __builtin_fmaf(acc[i][0][r], KSC, cn_[0]);                  \
      const float s1_ = __builtin_fmaf(acc[i][1][r], KSC, cn_[1]);                  \
      const float s2_ = __builtin_fmaf(acc[i][2][r], KSC, cn_[2]);                  \
      const float s3_ = __builtin_fmaf(acc[i][3][r], KSC, cn_[3]);                  \
      const float rm_ = fminf(fminf(s0_, s1_), fminf(s2_, s3_));                    \
      if (PASS != 1) {                                                              \
        vmin[row_] = fminf(vmin[row_], rm_);                                        \
        if (PASS == 3) {                                                            \
          if ((r & 1) == 0) prev_ = rm_;                                            \
          else sb_[(unsigned)((i * 2 + (r >> 1)) * 64)] = pack_f16x2(prev_, rm_);   \
        }                                                                           \
      } else if (rm_ <= thr[row_]) { /* exact early-out: min_j > thr => none */     \
        const float sv_[4] = {s0_, s1_, s2_, s3_};                                  \
        _Pragma("unroll") for (int j = 0; j < 4; ++j) {                             \
          if (sv_[j] <= thr[row_]) {                                                \
            const int slot_ = atomicAdd(paircount, 1);                              \
            if (slot_ < CAP_PAIRS)                                                  \
              pairs[slot_] = ((unsigned)qrow[row_] << 13) |                         \
                             (unsigned)(k0_ + wn * 64 + j * 16 + col);              \
          }                                                                         \
        }                                                                           \
      }                                                                             \
    }                                                                               \
  } while (0)

  for (int nt = 0; nt < 7; ++nt) {
    ZEROACC;
#pragma unroll
    for (int ct = 0; ct < 8; ++ct) CHUNK(ct, true, nt * 8 + ct + 2, 2);
    SCORING(nt);
  }
  // nt = 7 epilogue: stop staging at chunk 63, then drain
  ZEROACC;
  CHUNK(0, true, 58, 2);
  CHUNK(1, true, 59, 2);
  CHUNK(2, true, 60, 2);
  CHUNK(3, true, 61, 2);
  CHUNK(4, true, 62, 2);
  CHUNK(5, true, 63, 2);
  CHUNK(6, false, 0, 0);
  CHUNK(7, false, 0, 3);
  SCORING(7);

#undef STAGE_B
#undef CHUNK
#undef ZEROACC
#undef SCORING

  if (PASS != 1) {
    // cross-col min (value only), then atomicMin per row
#pragma unroll
    for (int row = 0; row < 16; ++row) {
      float v = vmin[row];
      v = fminf(v, __shfl_xor(v, 1, 64));
      v = fminf(v, __shfl_xor(v, 2, 64));
      v = fminf(v, __shfl_xor(v, 4, 64));
      v = fminf(v, __shfl_xor(v, 8, 64));
      if (col == 0) atomicMin(&gmin[qrow[row]], f2mono(v));
    }
  }
}

__global__ __launch_bounds__(256, 2) void gemm_pass1(const char* __restrict__ At,
                                                     const char* __restrict__ Bt,
                                                     const float* __restrict__ cbnorm,
                                                     unsigned* __restrict__ gmin) {
  gemm_body<0>(At, Bt, cbnorm, gmin, nullptr, nullptr, nullptr);
}

__global__ __launch_bounds__(256, 2) void gemm_pass1m(const char* __restrict__ At,
                                                      const char* __restrict__ Bt,
                                                      const float* __restrict__ cbnorm,
                                                      unsigned* __restrict__ gmin,
                                                      unsigned* __restrict__ memo) {
  gemm_body<3>(At, Bt, cbnorm, gmin, nullptr, nullptr, memo);
}

__global__ __launch_bounds__(256, 2) void gemm_pass2(const char* __restrict__ At,
                                                     const char* __restrict__ Bt,
                                                     const float* __restrict__ cbnorm,
                                                     unsigned* __restrict__ gmin,
                                                     unsigned* __restrict__ pairs,
                                                     int* __restrict__ paircount) {
  gemm_body<1>(At, Bt, cbnorm, gmin, pairs, paircount, nullptr);
}

// ---------------------------------------------------------------------------
// scan_exact: stream the 64 MiB fp16 group-min memo (decode R9/R10-verified);
// for each hit (stored rm <= gmin[q]+MARGIN+RM_ERR), the whole wave rescores
// the 4-k group with the R4-verified exact fp32 chain and atomicMin's the
// per-q winner. Per-lane hit bitmask; wave-coop loop via ballot/ffs/shfl.
// id encoding: (q << 11) | (ntile << 5) | (wn << 4) | col.
// ---------------------------------------------------------------------------
__global__ __launch_bounds__(256) void scan_exact(const unsigned* __restrict__ memo,
                                                  const unsigned* __restrict__ gmin,
                                                  const float* __restrict__ zT,
                                                  const float* __restrict__ cb,
                                                  const float* __restrict__ cbnorm,
                                                  const float* __restrict__ znorm,
                                                  unsigned long long* __restrict__ packed) {
  const unsigned NU4 = 4194304u;  // 64 MiB / 16
  const unsigned stride = gridDim.x * blockDim.x;  // 524288 divides NU4: uniform trip count
  const int lane = threadIdx.x & 63;
  for (unsigned U = blockIdx.x * 256 + threadIdx.x; U < NU4; U += stride) {
    const uint4 v = ((const uint4*)memo)[U];
    const unsigned u = U << 2;
    const unsigned lane0 = u & 63, col0 = lane0 & 15, quad = lane0 >> 4;
    const unsigned rp = (u >> 6) & 7;
    const unsigned w = (u >> 9) & 3;
    const unsigned t = (u >> 11) & 7;
    const unsigned blk = u >> 14;
    const unsigned mt = blk >> 3, slice = blk & 7;
    const unsigned wm = w >> 1, wn = w & 1;
    const unsigned ntile = slice * 8u + t;
    const unsigned row0 = rp * 2u;
    const int q0 = (int)(mt * 128u + wm * 64u + (row0 >> 2) * 16u + quad * 4u + (row0 & 3u));
    const float thr0 = mono2f(gmin[q0]) + (MARGIN + RM_ERR);
    const float thr1 = mono2f(gmin[q0 + 1]) + (MARGIN + RM_ERR);
    const unsigned wv[4] = {v.x, v.y, v.z, v.w};
    unsigned hm = 0;  // bit = wi*2 + h  (h=0 -> q0, h=1 -> q0+1)
#pragma unroll
    for (int wi = 0; wi < 4; ++wi) {
      const float lo = (float)__builtin_bit_cast(_Float16, (unsigned short)(wv[wi] & 0xffffu));
      const float hi = (float)__builtin_bit_cast(_Float16, (unsigned short)(wv[wi] >> 16));
      if (lo <= thr0) hm |= 1u << (wi * 2);
      if (hi <= thr1) hm |= 1u << (wi * 2 + 1);
    }
    // wave-cooperative rescore of each hit (rare: ~19K hits / 33.5M groups)
    while (true) {
      const unsigned long long act = __ballot(hm != 0);
      if (!act) break;
      const int src = (int)(__ffsll((unsigned long long)act) - 1);
      unsigned myid = 0;
      {
        const int bit = __ffs((int)hm) - 1;
        if (bit >= 0) {
          const unsigned wi = (unsigned)bit >> 1, h = (unsigned)bit & 1;
          const unsigned kid = (ntile << 5) | (wn << 4) | (col0 + wi);
          myid = ((unsigned)(q0 + (int)h) << 11) | kid;
        }
      }
      const unsigned id = (unsigned)__shfl((int)myid, src, 64);
      const int q = (int)(id >> 11);
      const int base = (int)(((id >> 5) & 63u) * 128u + ((id >> 4) & 1u) * 64u + (id & 15u));
      const float4 zv = ((const float4*)(zT + (size_t)q * FEAT))[lane];
      const float zn = znorm[q];
      unsigned long long best = ~0ull;
#pragma unroll
      for (int j = 0; j < 4; ++j) {
        const int k = base + j * 16;
        const float4 cv = ((const float4*)(cb + (size_t)k * FEAT))[lane];
        float d = __builtin_fmaf(zv.w, cv.w,
                  __builtin_fmaf(zv.z, cv.z,
                  __builtin_fmaf(zv.y, cv.y, __fmul_rn(zv.x, cv.x))));
#pragma unroll
        for (int dd = 1; dd < 64; dd <<= 1) d = __fadd_rn(d, __shfl_xor(d, dd, 64));
        const float s = __fadd_rn(__fadd_rn(__fmul_rn(-2.0f, d), zn), cbnorm[k]);
        const unsigned long long key = ((unsigned long long)f2mono(s) << 32) | (unsigned)k;
        best = (key < best) ? key : best;
      }
      if (lane == 0) atomicMin(&packed[q], best);
      if (lane == src) hm &= hm - 1;  // clear processed hit
    }
  }
}

// ---------------------------------------------------------------------------
// Exact fp32 rescore of (q,k) pairs (fallback path, R4-verified machinery).
// ---------------------------------------------------------------------------
__global__ __launch_bounds__(256) void exact_cand(const float* __restrict__ zT,
                                                  const float* __restrict__ cb,
                                                  const float* __restrict__ cbnorm,
                                                  const float* __restrict__ znorm,
                                                  const unsigned* __restrict__ pairs,
                                                  const int* __restrict__ paircount,
                                                  unsigned long long* __restrict__ packed) {
  const int cnt = min(*paircount, CAP_PAIRS);
  const int gw = (blockIdx.x * 256 + threadIdx.x) >> 6;
  const int nw = (gridDim.x * 256) >> 6;
  const int lane = threadIdx.x & 63;
  for (int p = gw; p < cnt; p += nw) {
    const unsigned qk = pairs[p];
    const int q = qk >> 13, k = qk & 8191;
    const float4 cv = ((const float4*)(cb + (size_t)k * FEAT))[lane];
    const float4 zv = ((const float4*)(zT + (size_t)q * FEAT))[lane];
    float d = __builtin_fmaf(zv.w, cv.w,
              __builtin_fmaf(zv.z, cv.z,
              __builtin_fmaf(zv.y, cv.y, __fmul_rn(zv.x, cv.x))));
#pragma unroll
    for (int dd = 1; dd < 64; dd <<= 1) d = __fadd_rn(d, __shfl_xor(d, dd, 64));
    const float s = __fadd_rn(__fadd_rn(__fmul_rn(-2.0f, d), znorm[q]), cbnorm[k]);
    if (lane == 0) {
      const unsigned long long key = ((unsigned long long)f2mono(s) << 32) | (unsigned)k;
      atomicMin(&packed[q], key);
    }
  }
}

// ---------------------------------------------------------------------------
// Gather: zq[b][c][hw] = cb[idx]; idx as float appended after zq.
// ---------------------------------------------------------------------------
__global__ __launch_bounds__(256) void vq_gather(const float* __restrict__ cb,
                                                 const unsigned long long* __restrict__ packed,
                                                 float* __restrict__ out) {
  const int q0 = blockIdx.x * 64;
  const int nl = threadIdx.x & 63;
  const int cg = threadIdx.x >> 6;
  const int q = q0 + nl;
  const int kq = (int)((unsigned)packed[q] & 8191u);
  const int b = q >> 10, hw = q & 1023;
  const float4* cb4 = (const float4*)cb;
#pragma unroll
  for (int t = 0; t < 16; ++t) {
    const int cc = cg + t * 4;
    const float4 v = cb4[kq * 64 + cc];
    const int base = b * (FEAT * 1024) + (cc * 4) * 1024 + hw;
    out[base] = v.x;
    out[base + 1024] = v.y;
    out[base + 2048] = v.z;
    out[base + 3072] = v.w;
  }
  if (threadIdx.x < 64) {
    const int qq = q0 + threadIdx.x;
    out[ZQ_ELEMS + qq] = (float)(int)((unsigned)packed[qq] & 8191u);
  }
}

extern "C" void kernel_launch(void* const* d_in, const int* in_sizes, int n_in,
                              void* d_out, int out_size, void* d_ws, size_t ws_size,
                              hipStream_t stream) {
  const float* z = (const float*)d_in[0];
  const float* cb = (const float*)d_in[1];
  char* w = (char*)d_ws;
  // ws layout: ~30 MiB fixed + 64 MiB group-min memo at MEMO_OFF
  char* At = w;                                            // 8 MB
  char* Bt = w + 8388608;                                  // 4 MB
  float* zT = (float*)(w + 12582912);                      // 16 MB
  float* cbnorm = (float*)(w + 29360128);                  // 32 KB
  float* znorm = (float*)(w + 29392896);                   // 64 KB
  unsigned* gmin = (unsigned*)(w + 29458432);              // 64 KB
  int* paircount = (int*)(w + 29523968);                   // 256 B
  unsigned* pairs = (unsigned*)(w + 29524224);             // 1 MB (fallback only)
  unsigned long long* packed = (unsigned long long*)(w + 30572800);  // 128 KB
  unsigned* memo = (unsigned*)(w + MEMO_OFF);              // 64 MiB fp16 group-mins

  const bool use_memo = ws_size >= (size_t)(MEMO_OFF + MEMO_BYTES);

  prep<<<PREP_BLOCKS, 256, 0, stream>>>(cb, z, cbnorm, At, zT, Bt,
                                        gmin, packed, paircount);
  znorm_zt<<<NQ / 16, 256, 0, stream>>>(zT, znorm);
  if (use_memo) {
    gemm_pass1m<<<(NQ / 128) * NSLICE, 256, 0, stream>>>(At, Bt, cbnorm, gmin, memo);
    scan_exact<<<2048, 256, 0, stream>>>(memo, gmin, zT, cb, cbnorm, znorm, packed);
  } else {
    gemm_pass1<<<(NQ / 128) * NSLICE, 256, 0, stream>>>(At, Bt, cbnorm, gmin);
    gemm_pass2<<<(NQ / 128) * NSLICE, 256, 0, stream>>>(At, Bt, cbnorm, gmin, pairs, paircount);
    exact_cand<<<512, 256, 0, stream>>>(zT, cb, cbnorm, znorm, pairs, paircount, packed);
  }
  vq_gather<<<NQ / 64, 256, 0, stream>>>(cb, packed, (float*)d_out);
}

// Round 12
// 182.238 us; speedup vs baseline: 4.2729x; 1.0283x over previous
//
#include <hip/hip_runtime.h>
#include <stdint.h>

#define FEAT 256
#define CODES 8192
#define NQ 16384                 // 16*32*32
#define ZQ_ELEMS (NQ * FEAT)
#define MARGIN 2e-3f             // = 2e bound on fp16 score error (R4-validated)
#define RM_ERR 1.0e-3f           // fp16 RNE storage err bound for |rm| < 2
#define NSLICE 8
#define CAP_PAIRS (1 << 18)      // 256K (fallback path only)
#define KSC (-0.0078125f)        // descale: acc * -2/256
#define MEMO_OFF 31457280ull     // 30 MiB: right after fixed ws region
#define MEMO_BYTES 67108864ull   // 64 MiB fp16 group-mins

typedef _Float16 f16x8 __attribute__((ext_vector_type(8)));
typedef float f32x4 __attribute__((ext_vector_type(4)));

__device__ __forceinline__ void async_lds16(void* lds, const void* g) {
  __builtin_amdgcn_global_load_lds(
      (const __attribute__((address_space(1))) void*)(uintptr_t)(g),
      (__attribute__((address_space(3))) void*)(uint32_t)(uintptr_t)(lds),
      16, 0, 0);
}

// monotone float<->uint order transform
__device__ __forceinline__ unsigned f2mono(float v) {
  unsigned u = __float_as_uint(v);
  return (u & 0x80000000u) ? ~u : (u | 0x80000000u);
}
__device__ __forceinline__ float mono2f(unsigned t) {
  unsigned u = (t & 0x80000000u) ? (t & 0x7fffffffu) : ~t;
  return __uint_as_float(u);
}
__device__ __forceinline__ unsigned pack_f16x2(float a, float b) {
  unsigned short ha = __builtin_bit_cast(unsigned short, (_Float16)a);
  unsigned short hb = __builtin_bit_cast(unsigned short, (_Float16)b);
  return (unsigned)ha | ((unsigned)hb << 16);
}

// ---------------------------------------------------------------------------
// numpy pairwise sum-of-squares replication (verified R1-R4, absmax 0).
// ---------------------------------------------------------------------------
template <int STRIDE>
__device__ __forceinline__ float pairwise256_sq(const float* __restrict__ base, int lane16) {
  const int h = lane16 >> 3, j = lane16 & 7;
  const float* p = base + (h * 128 + j) * STRIDE;
  float x = p[0];
  float r = __fmul_rn(x, x);
#pragma unroll
  for (int i = 1; i < 16; ++i) {
    float y = p[i * 8 * STRIDE];
    r = __fadd_rn(r, __fmul_rn(y, y));
  }
  r = __fadd_rn(r, __shfl_xor(r, 1, 64));
  r = __fadd_rn(r, __shfl_xor(r, 2, 64));
  r = __fadd_rn(r, __shfl_xor(r, 4, 64));
  float other = __shfl_xor(r, 8, 64);
  float lo = (h == 0) ? r : other;
  float hi = (h == 0) ? other : r;
  return __fadd_rn(lo, hi);
}

// ---------------------------------------------------------------------------
// prep: fused {cbnorm | convA | convB | buffer-init} via block-range dispatch.
// convA now emits At in FRAGMENT-LINEAR order (f = wm*256 + i*64 + lane,
// 16B per fragment, content = row (wm*64+i*16+(lane&15)), K-elems
// ct*32+(lane>>4)*8..+7) -- byte-identical fragment CONTENT to what the old
// staged+swizzled LDS path delivered to the MFMA (cancelling swizzles), so
// GEMM can load A straight to registers with coalesced dwordx4.
// blocks [0,512): cbnorm; [512,1536): convA; [1536,2048): convB;
// [2048,2112): init gmin/packed/paircount.
// ---------------------------------------------------------------------------
#define PREP_BLOCKS 2112
__global__ __launch_bounds__(256) void prep(const float* __restrict__ cb,
                                            const float* __restrict__ z,
                                            float* __restrict__ cbnorm,
                                            char* __restrict__ At, float* __restrict__ zT,
                                            char* __restrict__ Bt,
                                            unsigned* __restrict__ gmin,
                                            unsigned long long* __restrict__ packed,
                                            int* __restrict__ paircount) {
  __shared__ __align__(16) char smem[128 * 40 * 2 + 128 * 36 * 4];
  const int bb0 = blockIdx.x;
  const int t = threadIdx.x;
  if (bb0 < 512) {
    // ---- cbnorm ----
    const int g = (bb0 * 256 + t) >> 4;   // [0, 8192)
    const int lane16 = t & 15;
    float v = pairwise256_sq<1>(cb + g * FEAT, lane16);
    if (lane16 == 0) cbnorm[g] = v;
  } else if (bb0 < 1536) {
    // ---- convA ----
    _Float16* T = (_Float16*)smem;
    float* Tf = (float*)(smem + 128 * 40 * 2);
    const int blk = bb0 - 512;
    const int mt = blk >> 3, ct = blk & 7;
    const int q0 = mt * 128, bb = q0 >> 10, hw0 = q0 & 1023;
    const int c0 = ct * 32;
#pragma unroll
    for (int it = 0; it < 16; ++it) {
      const int cc = it * 2 + (t >> 7);
      const int qi = t & 127;
      float v = z[bb * (FEAT * 1024) + (c0 + cc) * 1024 + hw0 + qi];
      T[qi * 40 + cc] = (_Float16)v;
      Tf[qi * 36 + cc] = v;
    }
    __syncthreads();
    // fragment-linear At: thread t emits fragments f = 2t, 2t+1
#pragma unroll
    for (int g2 = 0; g2 < 2; ++g2) {
      const int f = t * 2 + g2;
      const int fwm = f >> 8, fi = (f >> 6) & 3, fl = f & 63;
      const int row = fwm * 64 + fi * 16 + (fl & 15);
      const int kg = fl >> 4;
      const float4 frag = *(const float4*)&T[row * 40 + kg * 8];
      *(float4*)(At + (size_t)(mt * 8 + ct) * 8192 + (size_t)f * 16) = frag;
    }
    const int r = t >> 1, h = t & 1;
    float* zrow = zT + (size_t)(q0 + r) * FEAT + c0 + h * 16;
#pragma unroll
    for (int e = 0; e < 4; ++e)
      *(float4*)(zrow + e * 4) = *(const float4*)&Tf[r * 36 + h * 16 + e * 4];
  } else if (bb0 < 2048) {
    // ---- convB (fragment-linear fp16, x256; verified R1-R11) ----
    const int T4 = (bb0 - 1536) * 256 + t;   // [0, 131072)
    const int K = T4 >> 4, part = T4 & 15;
    const float* src = cb + (size_t)K * FEAT + part * 16;
    const int nt = K >> 7, rem = K & 127;
    const int wn = rem >> 6, j = (rem >> 4) & 3, llo = rem & 15;
#pragma unroll
    for (int g = 0; g < 2; ++g) {
      const int c0 = part * 16 + g * 8;
      const int ct = c0 >> 5, lhi = (c0 >> 3) & 3;
      const int cg = nt * 8 + ct;
      f16x8 o;
#pragma unroll
      for (int e = 0; e < 8; ++e) o[e] = (_Float16)(src[g * 8 + e] * 256.0f);
      const size_t s = ((size_t)((cg * 2 + wn) * 4 + j) << 6) + (size_t)(lhi * 16 + llo);
      *(f16x8*)(Bt + s * 16) = o;
    }
  } else {
    // ---- init ----
    const int bi = bb0 - 2048;
    const int idx = bi * 256 + t;   // [0, 16384)
    gmin[idx] = 0xFFFFFFFFu;
    packed[idx] = ~0ull;
    if (bi == 0 && t < 64) paircount[t] = 0;
  }
}

// ---------------------------------------------------------------------------
// znorm_zt: znorm[q] from the contiguous transposed copy zT (bit-identical
// op order to the original strided read -- verified R11, absmax 0).
// ---------------------------------------------------------------------------
__global__ __launch_bounds__(256) void znorm_zt(const float* __restrict__ zT,
                                                float* __restrict__ znorm) {
  const int q = (blockIdx.x * 256 + threadIdx.x) >> 4;   // [0, 16384)
  const int lane16 = threadIdx.x & 15;
  float v = pairwise256_sq<1>(zT + (size_t)q * FEAT, lane16);
  if (lane16 == 0) znorm[q] = v;
}

// ---------------------------------------------------------------------------
// GEMM body, RESTRUCTURED (R12): A held entirely in REGISTERS (32 x f16x8 =
// 128 VGPR, loaded once, coalesced from fragment-linear At). LDS is only a
// 4-slot B ring (32 KB): stage issued 3 chunks ahead, counted vmcnt(4)
// (never drained mid-loop), ONE raw s_barrier per chunk (the staged buffer
// was consumed 4 chunks ago -- its readers are already past the intervening
// barriers). MFMA operand streams identical to R2-R11 -> identical acc ->
// absmax 0.  PASS semantics unchanged:
// PASS=0: per-row running min -> atomicMin gmin[q].
// PASS=1: (fallback pass2) push (q<<13|k) for score <= gmin[q]+MARGIN.
// PASS=3: PASS0 + store per-(row,tile) 4-k group-min as packed fp16x2
//         (memo layout identical to R9-R11, scan_exact-verified).
// ---------------------------------------------------------------------------
template <int PASS>
__device__ __forceinline__ void gemm_body(const char* __restrict__ At,
                                          const char* __restrict__ Bt,
                                          const float* __restrict__ cbnorm,
                                          unsigned* __restrict__ gmin,
                                          unsigned* __restrict__ pairs,
                                          int* __restrict__ paircount,
                                          unsigned* __restrict__ memo) {
  __shared__ __align__(16) char Bs[4][8192];   // 4-slot ring, 32 KB

  const int tid = threadIdx.x;
  const int slice = blockIdx.x & 7, mt = blockIdx.x >> 3;
  const int wave = tid >> 6, lane = tid & 63;
  const int wm = wave >> 1, wn = wave & 1;
  const int col = lane & 15, quad = lane >> 4;

  const char* Abase = At + (size_t)(mt * 8) * 8192;
  const char* Bslice = Bt + (size_t)slice * 524288;

  int qrow[16];
#pragma unroll
  for (int row = 0; row < 16; ++row)
    qrow[row] = mt * 128 + wm * 64 + (row >> 2) * 16 + quad * 4 + (row & 3);

  float vmin[16], thr[16];
#pragma unroll
  for (int row = 0; row < 16; ++row) vmin[row] = 3.4e38f;
  if (PASS == 1) {
    // oldest vmem ops: complete before the counted-vmcnt regime starts
#pragma unroll
    for (int row = 0; row < 16; ++row) thr[row] = mono2f(gmin[qrow[row]]) + MARGIN;
  }

  // ---- A fragments -> registers (coalesced dwordx4; fully static indexing)
  f16x8 af[8][4];
#pragma unroll
  for (int ct = 0; ct < 8; ++ct)
#pragma unroll
    for (int i = 0; i < 4; ++i)
      af[ct][i] = *(const f16x8*)(Abase + (size_t)ct * 8192 +
                                  (size_t)(wm * 256 + i * 64 + lane) * 16);

#define STAGE_B(SLOT, CIDX)                                                         \
  do {                                                                              \
    const char* gs_ = Bslice + ((size_t)(CIDX) << 13) + wave * 2048 + lane * 16;    \
    async_lds16(Bs[SLOT] + wave * 2048, gs_);                                       \
    async_lds16(Bs[SLOT] + wave * 2048 + 1024, gs_ + 1024);                         \
  } while (0)

  // prologue: prime 3 slots (depth-3 pipeline)
  STAGE_B(0, 0);
  STAGE_B(1, 1);
  STAGE_B(2, 2);
  asm volatile("s_waitcnt vmcnt(4)" ::: "memory");  // af + stage0 complete
  __builtin_amdgcn_sched_barrier(0);
  __builtin_amdgcn_s_barrier();

  f32x4 acc[4][4];

  // Per-chunk step (global chunk c = nt*8 + CT; buf slot = CT&3 since 8%4==0).
  // WMODE 4: vmcnt(4) -> newest 4 outstanding = stages c+2,c+3; stage(c+1)
  // and any interleaved scoring loads/stores (older) complete. 2/0: drain
  // tail. 3: no wait (final chunk). ONE barrier per chunk: stage(c+3)
  // overwrites buf consumed at c-1, whose readers all passed barrier(c-1).
#define CHUNK(CT, STG, CNEXT, WMODE)                                                \
  do {                                                                              \
    f16x8 bf_[4];                                                                   \
    _Pragma("unroll") for (int j = 0; j < 4; ++j)                                   \
        bf_[j] = *(const f16x8*)(Bs[(CT) & 3] + wn * 4096 + j * 1024 + lane * 16);  \
    if (STG) {                                                                      \
      STAGE_B((CNEXT) & 3, CNEXT);                                                  \
      __builtin_amdgcn_sched_barrier(0);                                            \
    }                                                                               \
    asm volatile("s_waitcnt lgkmcnt(0)" ::: "memory");                              \
    __builtin_amdgcn_sched_barrier(0);                                              \
    _Pragma("unroll") for (int i = 0; i < 4; ++i)                                   \
        _Pragma("unroll") for (int j = 0; j < 4; ++j)                               \
            acc[i][j] = __builtin_amdgcn_mfma_f32_16x16x32_f16(af[CT][i], bf_[j],   \
                                                               acc[i][j], 0, 0, 0); \
    if ((WMODE) == 4) {                                                             \
      asm volatile("s_waitcnt vmcnt(4)" ::: "memory");                              \
      __builtin_amdgcn_sched_barrier(0);                                            \
    }                                                                               \
    if ((WMODE) == 2) {                                                             \
      asm volatile("s_waitcnt vmcnt(2)" ::: "memory");                              \
      __builtin_amdgcn_sched_barrier(0);                                            \
    }                                                                               \
    if ((WMODE) == 0) {                                                             \
      asm volatile("s_waitcnt vmcnt(0)" ::: "memory");                              \
      __builtin_amdgcn_sched_barrier(0);                                            \
    }                                                                               \
    __builtin_amdgcn_s_barrier();                                                   \
  } while (0)

#define ZEROACC                                                                     \
  do {                                                                              \
    _Pragma("unroll") for (int i = 0; i < 4; ++i)                                   \
        _Pragma("unroll") for (int j = 0; j < 4; ++j)                               \
            acc[i][j] = (f32x4){0.f, 0.f, 0.f, 0.f};                                \
  } while (0)

#define SCORING(NT)                                                                 \
  do {                                                                              \
    const int k0_ = (slice * 8 + (NT)) * 128;                                       \
    float cn_[4];                                                                   \
    _Pragma("unroll") for (int j = 0; j < 4; ++j)                                   \
        cn_[j] = cbnorm[k0_ + wn * 64 + j * 16 + col];                              \
    unsigned* sb_ = (PASS == 3)                                                     \
        ? memo + ((((unsigned)blockIdx.x * 8u + (unsigned)(NT)) * 4u +              \
                   (unsigned)wave) * 8u) * 64u + (unsigned)lane                     \
        : nullptr;                                                                  \
    float prev_ = 0.f;                                                              \
    _Pragma("unroll") for (int i = 0; i < 4; ++i)                                   \
        _Pragma("unroll") for (int r = 0; r < 4; ++r) {                             \
      const int row_ = i * 4 + r;                                                   \
      const float s0_ = __builtin_fmaf(acc[i][0][r], KSC, cn_[0]);                  \
      const float s1_ = __builtin_fmaf(acc[i][1][r], KSC, cn_[1]);                  \
      const float s2_ = __builtin_fmaf(acc[i][2][r], KSC, cn_[2]);                  \
      const float s3_ = __builtin_fmaf(acc[i][3][r], KSC, cn_[3]);                  \
      const float rm_ = fminf(fminf(s0_, s1_), fminf(s2_, s3_));                    \
      if (PASS != 1) {                                                              \
        vmin[row_] = fminf(vmin[row_], rm_);                                        \
        if (PASS == 3) {                                                            \
          if ((r & 1) == 0) prev_ = rm_;                                            \
          else sb_[(unsigned)((i * 2 + (r >> 1)) * 64)] = pack_f16x2(prev_, rm_);   \
        }                                                                           \
      } else if (rm_ <= thr[row_]) { /* exact early-out: min_j > thr => none */     \
        const float sv_[4] = {s0_, s1_, s2_, s3_};                                  \
        _Pragma("unroll") for (int j = 0; j < 4; ++j) {                             \
          if (sv_[j] <= thr[row_]) {                                                \
            const int slot_ = atomicAdd(paircount, 1);                              \
            if (slot_ < CAP_PAIRS)                                                  \
              pairs[slot_] = ((unsigned)qrow[row_] << 13) |                         \
                             (unsigned)(k0_ + wn * 64 + j * 16 + col);              \
          }                                                                         \
        }                                                                           \
      }                                                                             \
    }                                                                               \
  } while (0)

  for (int nt = 0; nt < 7; ++nt) {
    ZEROACC;
#pragma unroll
    for (int ct = 0; ct < 8; ++ct) CHUNK(ct, true, nt * 8 + ct + 3, 4);
    SCORING(nt);
  }
  // nt = 7 epilogue: last stage is chunk 60 -> 63; then drain tail
  ZEROACC;
  CHUNK(0, true, 59, 4);
  CHUNK(1, true, 60, 4);
  CHUNK(2, true, 61, 4);
  CHUNK(3, true, 62, 4);
  CHUNK(4, true, 63, 4);
  CHUNK(5, false, 0, 2);
  CHUNK(6, false, 0, 0);
  CHUNK(7, false, 0, 3);
  SCORING(7);

#undef STAGE_B
#undef CHUNK
#undef ZEROACC
#undef SCORING

  if (PASS != 1) {
    // cross-col min (value only), then atomicMin per row
#pragma unroll
    for (int row = 0; row < 16; ++row) {
      float v = vmin[row];
      v = fminf(v, __shfl_xor(v, 1, 64));
      v = fminf(v, __shfl_xor(v, 2, 64));
      v = fminf(v, __shfl_xor(v, 4, 64));
      v = fminf(v, __shfl_xor(v, 8, 64));
      if (col == 0) atomicMin(&gmin[qrow[row]], f2mono(v));
    }
  }
}

__global__ __launch_bounds__(256, 2) void gemm_pass1(const char* __restrict__ At,
                                                     const char* __restrict__ Bt,
                                                     const float* __restrict__ cbnorm,
                                                     unsigned* __restrict__ gmin) {
  gemm_body<0>(At, Bt, cbnorm, gmin, nullptr, nullptr, nullptr);
}

__global__ __launch_bounds__(256, 2) void gemm_pass1m(const char* __restrict__ At,
                                                      const char* __restrict__ Bt,
                                                      const float* __restrict__ cbnorm,
                                                      unsigned* __restrict__ gmin,
                                                      unsigned* __restrict__ memo) {
  gemm_body<3>(At, Bt, cbnorm, gmin, nullptr, nullptr, memo);
}

__global__ __launch_bounds__(256, 2) void gemm_pass2(const char* __restrict__ At,
                                                     const char* __restrict__ Bt,
                                                     const float* __restrict__ cbnorm,
                                                     unsigned* __restrict__ gmin,
                                                     unsigned* __restrict__ pairs,
                                                     int* __restrict__ paircount) {
  gemm_body<1>(At, Bt, cbnorm, gmin, pairs, paircount, nullptr);
}

// ---------------------------------------------------------------------------
// scan_exact: stream the 64 MiB fp16 group-min memo (decode R9-R11 verified);
// for each hit (stored rm <= gmin[q]+MARGIN+RM_ERR), the whole wave rescores
// the 4-k group with the R4-verified exact fp32 chain and atomicMin's the
// per-q winner. Per-lane hit bitmask; wave-coop loop via ballot/ffs/shfl.
// id encoding: (q << 11) | (ntile << 5) | (wn << 4) | col.
// ---------------------------------------------------------------------------
__global__ __launch_bounds__(256) void scan_exact(const unsigned* __restrict__ memo,
                                                  const unsigned* __restrict__ gmin,
                                                  const float* __restrict__ zT,
                                                  const float* __restrict__ cb,
                                                  const float* __restrict__ cbnorm,
                                                  const float* __restrict__ znorm,
                                                  unsigned long long* __restrict__ packed) {
  const unsigned NU4 = 4194304u;  // 64 MiB / 16
  const unsigned stride = gridDim.x * blockDim.x;  // 524288 divides NU4: uniform trip count
  const int lane = threadIdx.x & 63;
  for (unsigned U = blockIdx.x * 256 + threadIdx.x; U < NU4; U += stride) {
    const uint4 v = ((const uint4*)memo)[U];
    const unsigned u = U << 2;
    const unsigned lane0 = u & 63, col0 = lane0 & 15, quad = lane0 >> 4;
    const unsigned rp = (u >> 6) & 7;
    const unsigned w = (u >> 9) & 3;
    const unsigned t = (u >> 11) & 7;
    const unsigned blk = u >> 14;
    const unsigned mt = blk >> 3, slice = blk & 7;
    const unsigned wm = w >> 1, wn = w & 1;
    const unsigned ntile = slice * 8u + t;
    const unsigned row0 = rp * 2u;
    const int q0 = (int)(mt * 128u + wm * 64u + (row0 >> 2) * 16u + quad * 4u + (row0 & 3u));
    const float thr0 = mono2f(gmin[q0]) + (MARGIN + RM_ERR);
    const float thr1 = mono2f(gmin[q0 + 1]) + (MARGIN + RM_ERR);
    const unsigned wv[4] = {v.x, v.y, v.z, v.w};
    unsigned hm = 0;  // bit = wi*2 + h  (h=0 -> q0, h=1 -> q0+1)
#pragma unroll
    for (int wi = 0; wi < 4; ++wi) {
      const float lo = (float)__builtin_bit_cast(_Float16, (unsigned short)(wv[wi] & 0xffffu));
      const float hi = (float)__builtin_bit_cast(_Float16, (unsigned short)(wv[wi] >> 16));
      if (lo <= thr0) hm |= 1u << (wi * 2);
      if (hi <= thr1) hm |= 1u << (wi * 2 + 1);
    }
    // wave-cooperative rescore of each hit (rare: ~19K hits / 33.5M groups)
    while (true) {
      const unsigned long long act = __ballot(hm != 0);
      if (!act) break;
      const int src = (int)(__ffsll((unsigned long long)act) - 1);
      unsigned myid = 0;
      {
        const int bit = __ffs((int)hm) - 1;
        if (bit >= 0) {
          const unsigned wi = (unsigned)bit >> 1, h = (unsigned)bit & 1;
          const unsigned kid = (ntile << 5) | (wn << 4) | (col0 + wi);
          myid = ((unsigned)(q0 + (int)h) << 11) | kid;
        }
      }
      const unsigned id = (unsigned)__shfl((int)myid, src, 64);
      const int q = (int)(id >> 11);
      const int base = (int)(((id >> 5) & 63u) * 128u + ((id >> 4) & 1u) * 64u + (id & 15u));
      const float4 zv = ((const float4*)(zT + (size_t)q * FEAT))[lane];
      const float zn = znorm[q];
      unsigned long long best = ~0ull;
#pragma unroll
      for (int j = 0; j < 4; ++j) {
        const int k = base + j * 16;
        const float4 cv = ((const float4*)(cb + (size_t)k * FEAT))[lane];
        float d = __builtin_fmaf(zv.w, cv.w,
                  __builtin_fmaf(zv.z, cv.z,
                  __builtin_fmaf(zv.y, cv.y, __fmul_rn(zv.x, cv.x))));
#pragma unroll
        for (int dd = 1; dd < 64; dd <<= 1) d = __fadd_rn(d, __shfl_xor(d, dd, 64));
        const float s = __fadd_rn(__fadd_rn(__fmul_rn(-2.0f, d), zn), cbnorm[k]);
        const unsigned long long key = ((unsigned long long)f2mono(s) << 32) | (unsigned)k;
        best = (key < best) ? key : best;
      }
      if (lane == 0) atomicMin(&packed[q], best);
      if (lane == src) hm &= hm - 1;  // clear processed hit
    }
  }
}

// ---------------------------------------------------------------------------
// Exact fp32 rescore of (q,k) pairs (fallback path, R4-verified machinery).
// ---------------------------------------------------------------------------
__global__ __launch_bounds__(256) void exact_cand(const float* __restrict__ zT,
                                                  const float* __restrict__ cb,
                                                  const float* __restrict__ cbnorm,
                                                  const float* __restrict__ znorm,
                                                  const unsigned* __restrict__ pairs,
                                                  const int* __restrict__ paircount,
                                                  unsigned long long* __restrict__ packed) {
  const int cnt = min(*paircount, CAP_PAIRS);
  const int gw = (blockIdx.x * 256 + threadIdx.x) >> 6;
  const int nw = (gridDim.x * 256) >> 6;
  const int lane = threadIdx.x & 63;
  for (int p = gw; p < cnt; p += nw) {
    const unsigned qk = pairs[p];
    const int q = qk >> 13, k = qk & 8191;
    const float4 cv = ((const float4*)(cb + (size_t)k * FEAT))[lane];
    const float4 zv = ((const float4*)(zT + (size_t)q * FEAT))[lane];
    float d = __builtin_fmaf(zv.w, cv.w,
              __builtin_fmaf(zv.z, cv.z,
              __builtin_fmaf(zv.y, cv.y, __fmul_rn(zv.x, cv.x))));
#pragma unroll
    for (int dd = 1; dd < 64; dd <<= 1) d = __fadd_rn(d, __shfl_xor(d, dd, 64));
    const float s = __fadd_rn(__fadd_rn(__fmul_rn(-2.0f, d), znorm[q]), cbnorm[k]);
    if (lane == 0) {
      const unsigned long long key = ((unsigned long long)f2mono(s) << 32) | (unsigned)k;
      atomicMin(&packed[q], key);
    }
  }
}

// ---------------------------------------------------------------------------
// Gather: zq[b][c][hw] = cb[idx]; idx as float appended after zq.
// ---------------------------------------------------------------------------
__global__ __launch_bounds__(256) void vq_gather(const float* __restrict__ cb,
                                                 const unsigned long long* __restrict__ packed,
                                                 float* __restrict__ out) {
  const int q0 = blockIdx.x * 64;
  const int nl = threadIdx.x & 63;
  const int cg = threadIdx.x >> 6;
  const int q = q0 + nl;
  const int kq = (int)((unsigned)packed[q] & 8191u);
  const int b = q >> 10, hw = q & 1023;
  const float4* cb4 = (const float4*)cb;
#pragma unroll
  for (int t = 0; t < 16; ++t) {
    const int cc = cg + t * 4;
    const float4 v = cb4[kq * 64 + cc];
    const int base = b * (FEAT * 1024) + (cc * 4) * 1024 + hw;
    out[base] = v.x;
    out[base + 1024] = v.y;
    out[base + 2048] = v.z;
    out[base + 3072] = v.w;
  }
  if (threadIdx.x < 64) {
    const int qq = q0 + threadIdx.x;
    out[ZQ_ELEMS + qq] = (float)(int)((unsigned)packed[qq] & 8191u);
  }
}

extern "C" void kernel_launch(void* const* d_in, const int* in_sizes, int n_in,
                              void* d_out, int out_size, void* d_ws, size_t ws_size,
                              hipStream_t stream) {
  const float* z = (const float*)d_in[0];
  const float* cb = (const float*)d_in[1];
  char* w = (char*)d_ws;
  // ws layout: ~30 MiB fixed + 64 MiB group-min memo at MEMO_OFF
  char* At = w;                                            // 8 MB
  char* Bt = w + 8388608;                                  // 4 MB
  float* zT = (float*)(w + 12582912);                      // 16 MB
  float* cbnorm = (float*)(w + 29360128);                  // 32 KB
  float* znorm = (float*)(w + 29392896);                   // 64 KB
  unsigned* gmin = (unsigned*)(w + 29458432);              // 64 KB
  int* paircount = (int*)(w + 29523968);                   // 256 B
  unsigned* pairs = (unsigned*)(w + 29524224);             // 1 MB (fallback only)
  unsigned long long* packed = (unsigned long long*)(w + 30572800);  // 128 KB
  unsigned* memo = (unsigned*)(w + MEMO_OFF);              // 64 MiB fp16 group-mins

  const bool use_memo = ws_size >= (size_t)(MEMO_OFF + MEMO_BYTES);

  prep<<<PREP_BLOCKS, 256, 0, stream>>>(cb, z, cbnorm, At, zT, Bt,
                                        gmin, packed, paircount);
  znorm_zt<<<NQ / 16, 256, 0, stream>>>(zT, znorm);
  if (use_memo) {
    gemm_pass1m<<<(NQ / 128) * NSLICE, 256, 0, stream>>>(At, Bt, cbnorm, gmin, memo);
    scan_exact<<<2048, 256, 0, stream>>>(memo, gmin, zT, cb, cbnorm, znorm, packed);
  } else {
    gemm_pass1<<<(NQ / 128) * NSLICE, 256, 0, stream>>>(At, Bt, cbnorm, gmin);
    gemm_pass2<<<(NQ / 128) * NSLICE, 256, 0, stream>>>(At, Bt, cbnorm, gmin, pairs, paircount);
    exact_cand<<<512, 256, 0, stream>>>(zT, cb, cbnorm, znorm, pairs, paircount, packed);
  }
  vq_gather<<<NQ / 64, 256, 0, stream>>>(cb, packed, (float*)d_out);
}